// Round 1
// baseline (1080.259 us; speedup 1.0000x reference)
//
#include <hip/hip_runtime.h>
#include <hip/hip_bf16.h>

// Problem constants (fixed by the reference)
constexpr int NN   = 50000;            // nodes
constexpr int EE   = 800000;           // random edges
constexpr int ETOT = EE + NN;          // + self loops
constexpr float SLOPE  = 0.2f;
constexpr float EPS_BN = 1e-5f;

// ---------------------------------------------------------------- CSR build

__global__ __launch_bounds__(256) void count_kernel(const int* __restrict__ ei,
                                                    int* __restrict__ cnt) {
    int j = blockIdx.x * 256 + threadIdx.x;
    if (j >= ETOT) return;
    int dst = (j < EE) ? ei[EE + j] : (j - EE);
    atomicAdd(&cnt[dst], 1);
}

__global__ __launch_bounds__(1024) void scan_kernel(const int* __restrict__ cnt,
                                                    int* __restrict__ off) {
    __shared__ int lds[1024];
    const int T = 1024;
    const int CH = (NN + T - 1) / T;       // 49
    int t = threadIdx.x;
    int base = t * CH;
    int s = 0;
    for (int i = base; i < base + CH && i < NN; ++i) s += cnt[i];
    lds[t] = s;
    __syncthreads();
    for (int o = 1; o < T; o <<= 1) {
        int w = (t >= o) ? lds[t - o] : 0;
        __syncthreads();
        lds[t] += w;
        __syncthreads();
    }
    int run = lds[t] - s;                  // exclusive prefix
    for (int i = base; i < base + CH && i < NN; ++i) { off[i] = run; run += cnt[i]; }
    if (base < NN && base + CH >= NN) off[NN] = run;
}

__global__ __launch_bounds__(256) void fill_kernel(const int* __restrict__ ei,
                                                   int* __restrict__ cursor,
                                                   int* __restrict__ ssrc) {
    int j = blockIdx.x * 256 + threadIdx.x;
    if (j >= ETOT) return;
    int src, dst;
    if (j < EE) { src = ei[j]; dst = ei[EE + j]; }
    else        { src = dst = j - EE; }
    int pos = atomicAdd(&cursor[dst], 1);
    ssrc[pos] = src;
}

// ---------------------------------------------------------------- GEMM  h = bn(x) @ W
// X:[NN,FIN] row-major, W:[FIN,WOUT] row-major, Hout:[NN,WOUT]
template <int FIN, int WOUT, bool BN>
__global__ __launch_bounds__(256) void gemm_kernel(const float* __restrict__ X,
                                                   const float* __restrict__ W,
                                                   const float* __restrict__ scale,
                                                   const float* __restrict__ shift,
                                                   float* __restrict__ Hout) {
    constexpr int NTX = WOUT / 4;      // threads across columns (float4 each)
    constexpr int NTY = 256 / NTX;     // row groups
    constexpr int RB  = 8;             // rows per block
    constexpr int RPT = RB / NTY;      // rows per thread
    __shared__ float xs[RB][FIN];

    int row0 = blockIdx.x * RB;
    int t = threadIdx.x;
    for (int idx = t; idx < RB * FIN; idx += 256) {
        int r = idx / FIN, k = idx % FIN;
        float v = X[(size_t)(row0 + r) * FIN + k];
        if (BN) v = v * scale[k] + shift[k];
        xs[r][k] = v;
    }
    __syncthreads();

    int tx = t % NTX, ty = t / NTX;
    float acc[RPT][4];
    #pragma unroll
    for (int r = 0; r < RPT; ++r) { acc[r][0]=acc[r][1]=acc[r][2]=acc[r][3]=0.f; }

    const float* Wp = W + tx * 4;
    for (int k = 0; k < FIN; ++k) {
        float4 w = *reinterpret_cast<const float4*>(Wp + (size_t)k * WOUT);
        #pragma unroll
        for (int r = 0; r < RPT; ++r) {
            float xv = xs[ty * RPT + r][k];
            acc[r][0] += xv * w.x;
            acc[r][1] += xv * w.y;
            acc[r][2] += xv * w.z;
            acc[r][3] += xv * w.w;
        }
    }
    #pragma unroll
    for (int r = 0; r < RPT; ++r) {
        int row = row0 + ty * RPT + r;
        float4 o = make_float4(acc[r][0], acc[r][1], acc[r][2], acc[r][3]);
        *reinterpret_cast<float4*>(Hout + (size_t)row * WOUT + tx * 4) = o;
    }
}

// ---------------------------------------------------------------- per-node attention logits
// als[n,h] = sum_c H[n,h*C+c]*a_src[h*C+c] ; same for ald. One wave per node.
template <int HC>
__global__ __launch_bounds__(256) void alsd_kernel(const float* __restrict__ Hm,
                                                   const float* __restrict__ a_src,
                                                   const float* __restrict__ a_dst,
                                                   float* __restrict__ als,
                                                   float* __restrict__ ald) {
    constexpr int VW = HC / 64;
    int wid  = threadIdx.x >> 6;
    int lane = threadIdx.x & 63;
    int node = blockIdx.x * 4 + wid;

    float ssum = 0.f, dsum = 0.f;
    if constexpr (VW == 4) {
        float4 h4 = *reinterpret_cast<const float4*>(Hm + (size_t)node * HC + lane * 4);
        float4 as = *reinterpret_cast<const float4*>(a_src + lane * 4);
        float4 ad = *reinterpret_cast<const float4*>(a_dst + lane * 4);
        ssum = h4.x*as.x + h4.y*as.y + h4.z*as.z + h4.w*as.w;
        dsum = h4.x*ad.x + h4.y*ad.y + h4.z*ad.z + h4.w*ad.w;
    } else {
        float2 h2 = *reinterpret_cast<const float2*>(Hm + (size_t)node * HC + lane * 2);
        float2 as = *reinterpret_cast<const float2*>(a_src + lane * 2);
        float2 ad = *reinterpret_cast<const float2*>(a_dst + lane * 2);
        ssum = h2.x*as.x + h2.y*as.y;
        dsum = h2.x*ad.x + h2.y*ad.y;
    }
    #pragma unroll
    for (int o = 1; o < 16; o <<= 1) {
        ssum += __shfl_xor(ssum, o);
        dsum += __shfl_xor(dsum, o);
    }
    if ((lane & 15) == 0) {
        int hd = lane >> 4;
        als[node * 4 + hd] = ssum;
        ald[node * 4 + hd] = dsum;
    }
}

// ---------------------------------------------------------------- fused edge softmax + aggregate
// One wave per destination node. Out[d] = relu( sum_j alpha_j * H[src_j] + bias )
template <int HC>
__global__ __launch_bounds__(256) void attn_kernel(const float* __restrict__ Hm,
                                                   const int* __restrict__ off,
                                                   const int* __restrict__ ssrc,
                                                   const float* __restrict__ als,
                                                   const float* __restrict__ ald,
                                                   const float* __restrict__ bias,
                                                   float* __restrict__ Out) {
    constexpr int VW = HC / 64;
    int wid  = threadIdx.x >> 6;
    int lane = threadIdx.x & 63;
    int d    = blockIdx.x * 4 + wid;
    int head = lane >> 4;

    int e0 = off[d], e1 = off[d + 1];
    float ald4[4];
    #pragma unroll
    for (int h = 0; h < 4; ++h) ald4[h] = ald[d * 4 + h];

    // pass 1: per-head sum of exp(leaky_relu(logit))
    float sh[4] = {0.f, 0.f, 0.f, 0.f};
    for (int j = e0 + lane; j < e1; j += 64) {
        int src = ssrc[j];
        #pragma unroll
        for (int h = 0; h < 4; ++h) {
            float e = als[src * 4 + h] + ald4[h];
            e = (e > 0.f) ? e : SLOPE * e;
            sh[h] += __expf(e);
        }
    }
    #pragma unroll
    for (int h = 0; h < 4; ++h) {
        float v = sh[h];
        #pragma unroll
        for (int o = 1; o < 64; o <<= 1) v += __shfl_xor(v, o);
        sh[h] = v;
    }
    float inv_s = 1.f / (sh[head] + 1e-16f);

    // pass 2: weighted aggregation, whole wave walks the edge list together
    float acc[VW];
    #pragma unroll
    for (int v = 0; v < VW; ++v) acc[v] = 0.f;

    for (int j = e0; j < e1; ++j) {
        int src = ssrc[j];
        float e = als[src * 4 + head] + ald4[head];
        e = (e > 0.f) ? e : SLOPE * e;
        float alpha = __expf(e) * inv_s;
        if constexpr (VW == 4) {
            float4 hv = *reinterpret_cast<const float4*>(Hm + (size_t)src * HC + lane * 4);
            acc[0] += alpha * hv.x; acc[1] += alpha * hv.y;
            acc[2] += alpha * hv.z; acc[3] += alpha * hv.w;
        } else {
            float2 hv = *reinterpret_cast<const float2*>(Hm + (size_t)src * HC + lane * 2);
            acc[0] += alpha * hv.x; acc[1] += alpha * hv.y;
        }
    }

    #pragma unroll
    for (int v = 0; v < VW; ++v) {
        float o = acc[v] + bias[lane * VW + v];
        Out[(size_t)d * HC + lane * VW + v] = fmaxf(o, 0.f);
    }
}

// ---------------------------------------------------------------- batch norm
__global__ __launch_bounds__(256) void bnstats_kernel(const float* __restrict__ X,
                                                      float* __restrict__ sums) {
    int c  = threadIdx.x;          // 256 columns
    int r0 = blockIdx.x * 200;     // 250 blocks * 200 rows = 50000
    float s = 0.f, q = 0.f;
    for (int r = r0; r < r0 + 200; ++r) {
        float v = X[(size_t)r * 256 + c];
        s += v; q += v * v;
    }
    atomicAdd(&sums[c], s);
    atomicAdd(&sums[256 + c], q);
}

__global__ __launch_bounds__(256) void bnfinal_kernel(const float* __restrict__ sums,
                                                      const float* __restrict__ gamma,
                                                      const float* __restrict__ beta,
                                                      float* __restrict__ scale,
                                                      float* __restrict__ shift) {
    int c = threadIdx.x;
    float mean = sums[c] / (float)NN;
    float var  = sums[256 + c] / (float)NN - mean * mean;
    float inv  = rsqrtf(var + EPS_BN);
    float sc   = gamma[c] * inv;
    scale[c] = sc;
    shift[c] = beta[c] - mean * sc;
}

// ---------------------------------------------------------------- launch

extern "C" void kernel_launch(void* const* d_in, const int* in_sizes, int n_in,
                              void* d_out, int out_size, void* d_ws, size_t ws_size,
                              hipStream_t stream) {
    const float* x      = (const float*)d_in[0];
    const int*   ei     = (const int*)d_in[1];
    const float* W1     = (const float*)d_in[2];
    const float* a_s1   = (const float*)d_in[3];
    const float* a_d1   = (const float*)d_in[4];
    const float* b1     = (const float*)d_in[5];
    const float* W2     = (const float*)d_in[6];
    const float* a_s2   = (const float*)d_in[7];
    const float* a_d2   = (const float*)d_in[8];
    const float* b2     = (const float*)d_in[9];
    const float* W3     = (const float*)d_in[10];
    const float* a_s3   = (const float*)d_in[11];
    const float* a_d3   = (const float*)d_in[12];
    const float* b3     = (const float*)d_in[13];
    const float* gamma1 = (const float*)d_in[14];
    const float* beta1  = (const float*)d_in[15];
    const float* gamma2 = (const float*)d_in[16];
    const float* beta2  = (const float*)d_in[17];

    char* ws = (char*)d_ws;
    size_t o = 0;
    auto alloc = [&](size_t bytes) -> void* {
        void* p = ws + o;
        o = (o + bytes + 255) & ~size_t(255);
        return p;
    };
    float* bufA  = (float*)alloc((size_t)NN * 256 * 4);
    float* bufB  = (float*)alloc((size_t)NN * 256 * 4);
    float* als   = (float*)alloc((size_t)NN * 4 * 4);
    float* ald   = (float*)alloc((size_t)NN * 4 * 4);
    float* sums  = (float*)alloc(512 * 4);
    float* scale = (float*)alloc(256 * 4);
    float* shift = (float*)alloc(256 * 4);
    int*   off   = (int*)alloc((size_t)(NN + 1) * 4);
    int*   cur   = (int*)alloc((size_t)NN * 4);
    int*   cnt   = (int*)alloc((size_t)NN * 4);
    int*   ssrc  = (int*)alloc((size_t)ETOT * 4);
    (void)ws_size; (void)in_sizes; (void)n_in; (void)out_size;

    const int EB = (ETOT + 255) / 256;

    // --- CSR build (shared by all 3 layers)
    hipMemsetAsync(cnt, 0, (size_t)NN * 4, stream);
    count_kernel<<<EB, 256, 0, stream>>>(ei, cnt);
    scan_kernel<<<1, 1024, 0, stream>>>(cnt, off);
    hipMemcpyAsync(cur, off, (size_t)NN * 4, hipMemcpyDeviceToDevice, stream);
    fill_kernel<<<EB, 256, 0, stream>>>(ei, cur, ssrc);

    // --- layer 1: x[N,128] -> h1[N,256] (bufA) -> attn -> bufB
    gemm_kernel<128, 256, false><<<NN / 8, 256, 0, stream>>>(x, W1, nullptr, nullptr, bufA);
    alsd_kernel<256><<<NN / 4, 256, 0, stream>>>(bufA, a_s1, a_d1, als, ald);
    attn_kernel<256><<<NN / 4, 256, 0, stream>>>(bufA, off, ssrc, als, ald, b1, bufB);

    hipMemsetAsync(sums, 0, 512 * 4, stream);
    bnstats_kernel<<<250, 256, 0, stream>>>(bufB, sums);
    bnfinal_kernel<<<1, 256, 0, stream>>>(sums, gamma1, beta1, scale, shift);

    // --- layer 2: bn(bufB)[N,256] -> h2[N,256] (bufA) -> attn -> bufB
    gemm_kernel<256, 256, true><<<NN / 8, 256, 0, stream>>>(bufB, W2, scale, shift, bufA);
    alsd_kernel<256><<<NN / 4, 256, 0, stream>>>(bufA, a_s2, a_d2, als, ald);
    attn_kernel<256><<<NN / 4, 256, 0, stream>>>(bufA, off, ssrc, als, ald, b2, bufB);

    hipMemsetAsync(sums, 0, 512 * 4, stream);
    bnstats_kernel<<<250, 256, 0, stream>>>(bufB, sums);
    bnfinal_kernel<<<1, 256, 0, stream>>>(sums, gamma2, beta2, scale, shift);

    // --- layer 3: bn(bufB)[N,256] -> h3[N,128] (bufA) -> attn -> d_out
    gemm_kernel<256, 128, true><<<NN / 8, 256, 0, stream>>>(bufB, W3, scale, shift, bufA);
    alsd_kernel<128><<<NN / 4, 256, 0, stream>>>(bufA, a_s3, a_d3, als, ald);
    attn_kernel<128><<<NN / 4, 256, 0, stream>>>(bufA, off, ssrc, als, ald, b3, (float*)d_out);
}

// Round 2
// 621.952 us; speedup vs baseline: 1.7369x; 1.7369x over previous
//
#include <hip/hip_runtime.h>
#include <hip/hip_bf16.h>

// Problem constants (fixed by the reference)
constexpr int NN   = 50000;            // nodes
constexpr int EE   = 800000;           // random edges
constexpr int ETOT = EE + NN;          // + self loops
constexpr int NP   = 50048;            // rows padded to multiple of 128 (391*128)
constexpr float SLOPE  = 0.2f;
constexpr float EPS_BN = 1e-5f;

typedef __attribute__((ext_vector_type(8))) short bf16x8;
typedef __attribute__((ext_vector_type(4))) float f32x4;

__device__ inline float bf2f(unsigned short u) {
    union { unsigned int i; float f; } c; c.i = ((unsigned int)u) << 16; return c.f;
}

__device__ inline void gload16(const __hip_bfloat16* g, __hip_bfloat16* l) {
    __builtin_amdgcn_global_load_lds(
        (const __attribute__((address_space(1))) unsigned int*)g,
        (__attribute__((address_space(3))) unsigned int*)l, 16, 0, 0);
}

// ---------------------------------------------------------------- CSR build

__global__ __launch_bounds__(256) void count_kernel(const int* __restrict__ ei,
                                                    int* __restrict__ cnt) {
    int j = blockIdx.x * 256 + threadIdx.x;
    if (j >= ETOT) return;
    int dst = (j < EE) ? ei[EE + j] : (j - EE);
    atomicAdd(&cnt[dst], 1);
}

__global__ __launch_bounds__(1024) void scan_kernel(const int* __restrict__ cnt,
                                                    int* __restrict__ off) {
    __shared__ int lds[1024];
    const int T = 1024;
    const int CH = (NN + T - 1) / T;       // 49
    int t = threadIdx.x;
    int base = t * CH;
    int s = 0;
    for (int i = base; i < base + CH && i < NN; ++i) s += cnt[i];
    lds[t] = s;
    __syncthreads();
    for (int o = 1; o < T; o <<= 1) {
        int w = (t >= o) ? lds[t - o] : 0;
        __syncthreads();
        lds[t] += w;
        __syncthreads();
    }
    int run = lds[t] - s;                  // exclusive prefix
    for (int i = base; i < base + CH && i < NN; ++i) { off[i] = run; run += cnt[i]; }
    if (base < NN && base + CH >= NN) off[NN] = run;
}

__global__ __launch_bounds__(256) void fill_kernel(const int* __restrict__ ei,
                                                   int* __restrict__ cursor,
                                                   int* __restrict__ ssrc) {
    int j = blockIdx.x * 256 + threadIdx.x;
    if (j >= ETOT) return;
    int src, dst;
    if (j < EE) { src = ei[j]; dst = ei[EE + j]; }
    else        { src = dst = j - EE; }
    int pos = atomicAdd(&cursor[dst], 1);
    ssrc[pos] = src;
}

// ---------------------------------------------------------------- casts
// X (f32, optional BN affine) -> Xbf (bf16, [NP][F], pad rows zero-filled)
template <int F, bool BN>
__global__ __launch_bounds__(256) void cast_kernel(const float* __restrict__ X,
                                                   const float* __restrict__ scale,
                                                   const float* __restrict__ shift,
                                                   __hip_bfloat16* __restrict__ Xbf) {
    long idx = (long)blockIdx.x * 256 + threadIdx.x;     // 8 elems per thread
    long e0 = idx * 8;
    if (e0 >= (long)NP * F) return;
    int row = (int)(e0 / F);
    int col = (int)(e0 % F);
    __hip_bfloat16 o[8];
    if (row < NN) {
        float4 v0 = *reinterpret_cast<const float4*>(X + (size_t)row * F + col);
        float4 v1 = *reinterpret_cast<const float4*>(X + (size_t)row * F + col + 4);
        if (BN) {
            float4 s0 = *reinterpret_cast<const float4*>(scale + col);
            float4 s1 = *reinterpret_cast<const float4*>(scale + col + 4);
            float4 t0 = *reinterpret_cast<const float4*>(shift + col);
            float4 t1 = *reinterpret_cast<const float4*>(shift + col + 4);
            v0.x = v0.x * s0.x + t0.x; v0.y = v0.y * s0.y + t0.y;
            v0.z = v0.z * s0.z + t0.z; v0.w = v0.w * s0.w + t0.w;
            v1.x = v1.x * s1.x + t1.x; v1.y = v1.y * s1.y + t1.y;
            v1.z = v1.z * s1.z + t1.z; v1.w = v1.w * s1.w + t1.w;
        }
        o[0] = __float2bfloat16(v0.x); o[1] = __float2bfloat16(v0.y);
        o[2] = __float2bfloat16(v0.z); o[3] = __float2bfloat16(v0.w);
        o[4] = __float2bfloat16(v1.x); o[5] = __float2bfloat16(v1.y);
        o[6] = __float2bfloat16(v1.z); o[7] = __float2bfloat16(v1.w);
    } else {
        for (int j = 0; j < 8; ++j) o[j] = __float2bfloat16(0.f);
    }
    *reinterpret_cast<bf16x8*>(Xbf + e0) = *reinterpret_cast<bf16x8*>(o);
}

// W [FIN][WOUT] f32 -> WT [WOUT][FIN] bf16 (transposed for MFMA B-fragments)
template <int FIN, int WOUT>
__global__ __launch_bounds__(256) void castw_kernel(const float* __restrict__ W,
                                                    __hip_bfloat16* __restrict__ WT) {
    int i = blockIdx.x * 256 + threadIdx.x;
    if (i >= FIN * WOUT) return;
    int c = i / FIN, k = i % FIN;
    WT[i] = __float2bfloat16(W[(size_t)k * WOUT + c]);
}

// ---------------------------------------------------------------- MFMA GEMM
// A:[NP][FIN] bf16, BT:[WOUT][FIN] bf16, Hbf:[NP][WOUT] bf16
// 128x128 tile, 4 waves (2x2), 64x64 per wave, BK=32, mfma_f32_16x16x32_bf16
template <int FIN, int WOUT>
__global__ __launch_bounds__(256) void mgemm_kernel(const __hip_bfloat16* __restrict__ A,
                                                    const __hip_bfloat16* __restrict__ BT,
                                                    __hip_bfloat16* __restrict__ Hbf) {
    __shared__ __hip_bfloat16 As[128 * 32];
    __shared__ __hip_bfloat16 Bs[128 * 32];
    int t = threadIdx.x;
    int lane = t & 63, w = t >> 6;
    int row0 = blockIdx.x * 128;
    int col0 = blockIdx.y * 128;
    int wr = w >> 1, wc = w & 1;

    f32x4 acc[4][4];
    #pragma unroll
    for (int m = 0; m < 4; ++m)
        #pragma unroll
        for (int n = 0; n < 4; ++n) acc[m][n] = (f32x4){0.f, 0.f, 0.f, 0.f};

    // staging: wave w covers tile rows [w*32, w*32+32); lane l -> row w*32+i*16+l/4, 16B chunk l%4
    int srow = w * 32 + (lane >> 2);
    int sbc  = (lane & 3) * 8;                   // element offset of 16B chunk
    const __hip_bfloat16* gA0 = A  + (size_t)(row0 + srow)      * FIN + sbc;
    const __hip_bfloat16* gA1 = A  + (size_t)(row0 + srow + 16) * FIN + sbc;
    const __hip_bfloat16* gB0 = BT + (size_t)(col0 + srow)      * FIN + sbc;
    const __hip_bfloat16* gB1 = BT + (size_t)(col0 + srow + 16) * FIN + sbc;
    __hip_bfloat16* lA0 = As + w * 1024;
    __hip_bfloat16* lA1 = As + w * 1024 + 512;
    __hip_bfloat16* lB0 = Bs + w * 1024;
    __hip_bfloat16* lB1 = Bs + w * 1024 + 512;

    int rA = (wr * 64 + (lane & 15)) * 32 + (lane >> 4) * 8;   // element offset in As
    int rB = (wc * 64 + (lane & 15)) * 32 + (lane >> 4) * 8;

    for (int k0 = 0; k0 < FIN; k0 += 32) {
        gload16(gA0 + k0, lA0);
        gload16(gA1 + k0, lA1);
        gload16(gB0 + k0, lB0);
        gload16(gB1 + k0, lB1);
        __syncthreads();                     // compiler drains vmcnt before barrier
        bf16x8 af[4], bfr[4];
        #pragma unroll
        for (int m = 0; m < 4; ++m) af[m]  = *reinterpret_cast<const bf16x8*>(As + rA + m * 16 * 32);
        #pragma unroll
        for (int n = 0; n < 4; ++n) bfr[n] = *reinterpret_cast<const bf16x8*>(Bs + rB + n * 16 * 32);
        #pragma unroll
        for (int m = 0; m < 4; ++m)
            #pragma unroll
            for (int n = 0; n < 4; ++n)
                acc[m][n] = __builtin_amdgcn_mfma_f32_16x16x32_bf16(af[m], bfr[n], acc[m][n], 0, 0, 0);
        __syncthreads();
    }

    // epilogue: C/D layout col=lane&15, row=(lane>>4)*4+reg
    #pragma unroll
    for (int m = 0; m < 4; ++m) {
        #pragma unroll
        for (int n = 0; n < 4; ++n) {
            int r = row0 + wr * 64 + m * 16 + (lane >> 4) * 4;
            int c = col0 + wc * 64 + n * 16 + (lane & 15);
            #pragma unroll
            for (int j = 0; j < 4; ++j)
                Hbf[(size_t)(r + j) * WOUT + c] = __float2bfloat16(acc[m][n][j]);
        }
    }
}

// ---------------------------------------------------------------- per-node attention logits
template <int HC>
__global__ __launch_bounds__(256) void alsd_kernel(const __hip_bfloat16* __restrict__ Hm,
                                                   const float* __restrict__ a_src,
                                                   const float* __restrict__ a_dst,
                                                   float* __restrict__ als,
                                                   float* __restrict__ ald) {
    constexpr int VW = HC / 64;
    int wid  = threadIdx.x >> 6;
    int lane = threadIdx.x & 63;
    int node = blockIdx.x * 4 + wid;

    float ssum = 0.f, dsum = 0.f;
    if constexpr (VW == 4) {
        ushort4 h4 = *reinterpret_cast<const ushort4*>(Hm + (size_t)node * HC + lane * 4);
        float4 as = *reinterpret_cast<const float4*>(a_src + lane * 4);
        float4 ad = *reinterpret_cast<const float4*>(a_dst + lane * 4);
        float hx = bf2f(h4.x), hy = bf2f(h4.y), hz = bf2f(h4.z), hw = bf2f(h4.w);
        ssum = hx*as.x + hy*as.y + hz*as.z + hw*as.w;
        dsum = hx*ad.x + hy*ad.y + hz*ad.z + hw*ad.w;
    } else {
        ushort2 h2 = *reinterpret_cast<const ushort2*>(Hm + (size_t)node * HC + lane * 2);
        float2 as = *reinterpret_cast<const float2*>(a_src + lane * 2);
        float2 ad = *reinterpret_cast<const float2*>(a_dst + lane * 2);
        float hx = bf2f(h2.x), hy = bf2f(h2.y);
        ssum = hx*as.x + hy*as.y;
        dsum = hx*ad.x + hy*ad.y;
    }
    #pragma unroll
    for (int o = 1; o < 16; o <<= 1) {
        ssum += __shfl_xor(ssum, o);
        dsum += __shfl_xor(dsum, o);
    }
    if ((lane & 15) == 0) {
        int hd = lane >> 4;
        als[node * 4 + hd] = ssum;
        ald[node * 4 + hd] = dsum;
    }
}

// ---------------------------------------------------------------- fused edge softmax + aggregate
template <int HC>
__global__ __launch_bounds__(256) void attn_kernel(const __hip_bfloat16* __restrict__ Hm,
                                                   const int* __restrict__ off,
                                                   const int* __restrict__ ssrc,
                                                   const float* __restrict__ als,
                                                   const float* __restrict__ ald,
                                                   const float* __restrict__ bias,
                                                   float* __restrict__ Out) {
    constexpr int VW = HC / 64;
    int wid  = threadIdx.x >> 6;
    int lane = threadIdx.x & 63;
    int d    = blockIdx.x * 4 + wid;
    int head = lane >> 4;

    int e0 = off[d], e1 = off[d + 1];
    float ald4[4];
    #pragma unroll
    for (int h = 0; h < 4; ++h) ald4[h] = ald[d * 4 + h];

    // pass 1: per-head sum of exp(leaky_relu(logit))
    float sh[4] = {0.f, 0.f, 0.f, 0.f};
    for (int j = e0 + lane; j < e1; j += 64) {
        int src = ssrc[j];
        float4 a4 = *reinterpret_cast<const float4*>(als + (size_t)src * 4);
        float ev[4] = {a4.x, a4.y, a4.z, a4.w};
        #pragma unroll
        for (int h = 0; h < 4; ++h) {
            float e = ev[h] + ald4[h];
            e = (e > 0.f) ? e : SLOPE * e;
            sh[h] += __expf(e);
        }
    }
    #pragma unroll
    for (int h = 0; h < 4; ++h) {
        float v = sh[h];
        #pragma unroll
        for (int o = 1; o < 64; o <<= 1) v += __shfl_xor(v, o);
        sh[h] = v;
    }
    float inv_s = 1.f / (sh[head] + 1e-16f);

    // pass 2: weighted aggregation; wave walks the edge list together
    float acc[VW];
    #pragma unroll
    for (int v = 0; v < VW; ++v) acc[v] = 0.f;

    for (int j = e0; j < e1; ++j) {
        int src = ssrc[j];
        float e = als[(size_t)src * 4 + head] + ald4[head];
        e = (e > 0.f) ? e : SLOPE * e;
        float alpha = __expf(e) * inv_s;
        if constexpr (VW == 4) {
            ushort4 hv = *reinterpret_cast<const ushort4*>(Hm + (size_t)src * HC + lane * 4);
            acc[0] += alpha * bf2f(hv.x); acc[1] += alpha * bf2f(hv.y);
            acc[2] += alpha * bf2f(hv.z); acc[3] += alpha * bf2f(hv.w);
        } else {
            ushort2 hv = *reinterpret_cast<const ushort2*>(Hm + (size_t)src * HC + lane * 2);
            acc[0] += alpha * bf2f(hv.x); acc[1] += alpha * bf2f(hv.y);
        }
    }

    #pragma unroll
    for (int v = 0; v < VW; ++v) {
        float o = acc[v] + bias[lane * VW + v];
        Out[(size_t)d * HC + lane * VW + v] = fmaxf(o, 0.f);
    }
}

// ---------------------------------------------------------------- batch norm
__global__ __launch_bounds__(256) void bnstats_kernel(const float* __restrict__ X,
                                                      float* __restrict__ sums) {
    int c  = threadIdx.x;
    int r0 = blockIdx.x * 200;
    float s = 0.f, q = 0.f;
    for (int r = r0; r < r0 + 200; ++r) {
        float v = X[(size_t)r * 256 + c];
        s += v; q += v * v;
    }
    atomicAdd(&sums[c], s);
    atomicAdd(&sums[256 + c], q);
}

__global__ __launch_bounds__(256) void bnfinal_kernel(const float* __restrict__ sums,
                                                      const float* __restrict__ gamma,
                                                      const float* __restrict__ beta,
                                                      float* __restrict__ scale,
                                                      float* __restrict__ shift) {
    int c = threadIdx.x;
    float mean = sums[c] / (float)NN;
    float var  = sums[256 + c] / (float)NN - mean * mean;
    float inv  = rsqrtf(var + EPS_BN);
    float sc   = gamma[c] * inv;
    scale[c] = sc;
    shift[c] = beta[c] - mean * sc;
}

// ---------------------------------------------------------------- launch

extern "C" void kernel_launch(void* const* d_in, const int* in_sizes, int n_in,
                              void* d_out, int out_size, void* d_ws, size_t ws_size,
                              hipStream_t stream) {
    const float* x      = (const float*)d_in[0];
    const int*   ei     = (const int*)d_in[1];
    const float* W1     = (const float*)d_in[2];
    const float* a_s1   = (const float*)d_in[3];
    const float* a_d1   = (const float*)d_in[4];
    const float* b1     = (const float*)d_in[5];
    const float* W2     = (const float*)d_in[6];
    const float* a_s2   = (const float*)d_in[7];
    const float* a_d2   = (const float*)d_in[8];
    const float* b2     = (const float*)d_in[9];
    const float* W3     = (const float*)d_in[10];
    const float* a_s3   = (const float*)d_in[11];
    const float* a_d3   = (const float*)d_in[12];
    const float* b3     = (const float*)d_in[13];
    const float* gamma1 = (const float*)d_in[14];
    const float* beta1  = (const float*)d_in[15];
    const float* gamma2 = (const float*)d_in[16];
    const float* beta2  = (const float*)d_in[17];

    char* ws = (char*)d_ws;
    size_t o = 0;
    auto alloc = [&](size_t bytes) -> void* {
        void* p = ws + o;
        o = (o + bytes + 255) & ~size_t(255);
        return p;
    };
    float*           bufB = (float*)alloc((size_t)NN * 256 * 4);          // attn out f32
    __hip_bfloat16*  Xbf  = (__hip_bfloat16*)alloc((size_t)NP * 256 * 2); // GEMM A
    __hip_bfloat16*  Hbf  = (__hip_bfloat16*)alloc((size_t)NP * 256 * 2); // GEMM out
    __hip_bfloat16*  WT   = (__hip_bfloat16*)alloc((size_t)256 * 256 * 2);
    float* als   = (float*)alloc((size_t)NN * 4 * 4);
    float* ald   = (float*)alloc((size_t)NN * 4 * 4);
    float* sums  = (float*)alloc(512 * 4);
    float* scale = (float*)alloc(256 * 4);
    float* shift = (float*)alloc(256 * 4);
    int*   off   = (int*)alloc((size_t)(NN + 1) * 4);
    int*   cur   = (int*)alloc((size_t)NN * 4);
    int*   cnt   = (int*)alloc((size_t)NN * 4);
    int*   ssrc  = (int*)alloc((size_t)ETOT * 4);
    (void)ws_size; (void)in_sizes; (void)n_in; (void)out_size;

    const int EB = (ETOT + 255) / 256;

    // --- CSR build (shared by all 3 layers)
    hipMemsetAsync(cnt, 0, (size_t)NN * 4, stream);
    count_kernel<<<EB, 256, 0, stream>>>(ei, cnt);
    scan_kernel<<<1, 1024, 0, stream>>>(cnt, off);
    hipMemcpyAsync(cur, off, (size_t)NN * 4, hipMemcpyDeviceToDevice, stream);
    fill_kernel<<<EB, 256, 0, stream>>>(ei, cur, ssrc);

    // --- layer 1: x[N,128] -> h1 bf16 -> attn -> bufB
    cast_kernel<128, false><<<(int)(((long)NP * 128 / 8 + 255) / 256), 256, 0, stream>>>(x, nullptr, nullptr, Xbf);
    castw_kernel<128, 256><<<(128 * 256 + 255) / 256, 256, 0, stream>>>(W1, WT);
    mgemm_kernel<128, 256><<<dim3(NP / 128, 2), 256, 0, stream>>>(Xbf, WT, Hbf);
    alsd_kernel<256><<<NN / 4, 256, 0, stream>>>(Hbf, a_s1, a_d1, als, ald);
    attn_kernel<256><<<NN / 4, 256, 0, stream>>>(Hbf, off, ssrc, als, ald, b1, bufB);

    hipMemsetAsync(sums, 0, 512 * 4, stream);
    bnstats_kernel<<<250, 256, 0, stream>>>(bufB, sums);
    bnfinal_kernel<<<1, 256, 0, stream>>>(sums, gamma1, beta1, scale, shift);

    // --- layer 2
    cast_kernel<256, true><<<(int)(((long)NP * 256 / 8 + 255) / 256), 256, 0, stream>>>(bufB, scale, shift, Xbf);
    castw_kernel<256, 256><<<(256 * 256 + 255) / 256, 256, 0, stream>>>(W2, WT);
    mgemm_kernel<256, 256><<<dim3(NP / 128, 2), 256, 0, stream>>>(Xbf, WT, Hbf);
    alsd_kernel<256><<<NN / 4, 256, 0, stream>>>(Hbf, a_s2, a_d2, als, ald);
    attn_kernel<256><<<NN / 4, 256, 0, stream>>>(Hbf, off, ssrc, als, ald, b2, bufB);

    hipMemsetAsync(sums, 0, 512 * 4, stream);
    bnstats_kernel<<<250, 256, 0, stream>>>(bufB, sums);
    bnfinal_kernel<<<1, 256, 0, stream>>>(sums, gamma2, beta2, scale, shift);

    // --- layer 3
    cast_kernel<256, true><<<(int)(((long)NP * 256 / 8 + 255) / 256), 256, 0, stream>>>(bufB, scale, shift, Xbf);
    castw_kernel<256, 128><<<(256 * 128 + 255) / 256, 256, 0, stream>>>(W3, WT);
    mgemm_kernel<256, 128><<<dim3(NP / 128, 1), 256, 0, stream>>>(Xbf, WT, Hbf);
    alsd_kernel<128><<<NN / 4, 256, 0, stream>>>(Hbf, a_s3, a_d3, als, ald);
    attn_kernel<128><<<NN / 4, 256, 0, stream>>>(Hbf, off, ssrc, als, ald, b3, (float*)d_out);
}

// Round 3
// 489.539 us; speedup vs baseline: 2.2067x; 1.2705x over previous
//
#include <hip/hip_runtime.h>
#include <hip/hip_bf16.h>

// Problem constants (fixed by the reference)
constexpr int NN   = 50000;            // nodes
constexpr int EE   = 800000;           // random edges
constexpr int ETOT = EE + NN;          // + self loops
constexpr int NP   = 50048;            // rows padded to multiple of 128 (391*128)
constexpr float SLOPE  = 0.2f;
constexpr float EPS_BN = 1e-5f;

typedef __attribute__((ext_vector_type(8))) short bf16x8;
typedef __attribute__((ext_vector_type(4))) float f32x4;

__device__ inline float bf2f(unsigned short u) {
    union { unsigned int i; float f; } c; c.i = ((unsigned int)u) << 16; return c.f;
}

__device__ inline void gload16(const __hip_bfloat16* g, __hip_bfloat16* l) {
    __builtin_amdgcn_global_load_lds(
        (const __attribute__((address_space(1))) unsigned int*)g,
        (__attribute__((address_space(3))) unsigned int*)l, 16, 0, 0);
}

// ---------------------------------------------------------------- CSR build

__global__ __launch_bounds__(256) void count_kernel(const int* __restrict__ ei,
                                                    int* __restrict__ cnt) {
    int j = blockIdx.x * 256 + threadIdx.x;
    if (j >= ETOT) return;
    int dst = (j < EE) ? ei[EE + j] : (j - EE);
    atomicAdd(&cnt[dst], 1);
}

__global__ __launch_bounds__(1024) void scan_kernel(const int* __restrict__ cnt,
                                                    int* __restrict__ off) {
    __shared__ int lds[1024];
    const int T = 1024;
    const int CH = (NN + T - 1) / T;       // 49
    int t = threadIdx.x;
    int base = t * CH;
    int s = 0;
    for (int i = base; i < base + CH && i < NN; ++i) s += cnt[i];
    lds[t] = s;
    __syncthreads();
    for (int o = 1; o < T; o <<= 1) {
        int w = (t >= o) ? lds[t - o] : 0;
        __syncthreads();
        lds[t] += w;
        __syncthreads();
    }
    int run = lds[t] - s;                  // exclusive prefix
    for (int i = base; i < base + CH && i < NN; ++i) { off[i] = run; run += cnt[i]; }
    if (base < NN && base + CH >= NN) off[NN] = run;
}

__global__ __launch_bounds__(256) void fill_kernel(const int* __restrict__ ei,
                                                   int* __restrict__ cursor,
                                                   int* __restrict__ ssrc) {
    int j = blockIdx.x * 256 + threadIdx.x;
    if (j >= ETOT) return;
    int src, dst;
    if (j < EE) { src = ei[j]; dst = ei[EE + j]; }
    else        { src = dst = j - EE; }
    int pos = atomicAdd(&cursor[dst], 1);
    ssrc[pos] = src;
}

// ---------------------------------------------------------------- casts
template <int F, bool BN>
__global__ __launch_bounds__(256) void cast_kernel(const float* __restrict__ X,
                                                   const float* __restrict__ scale,
                                                   const float* __restrict__ shift,
                                                   __hip_bfloat16* __restrict__ Xbf) {
    long idx = (long)blockIdx.x * 256 + threadIdx.x;     // 8 elems per thread
    long e0 = idx * 8;
    if (e0 >= (long)NP * F) return;
    int row = (int)(e0 / F);
    int col = (int)(e0 % F);
    __hip_bfloat16 o[8];
    if (row < NN) {
        float4 v0 = *reinterpret_cast<const float4*>(X + (size_t)row * F + col);
        float4 v1 = *reinterpret_cast<const float4*>(X + (size_t)row * F + col + 4);
        if (BN) {
            float4 s0 = *reinterpret_cast<const float4*>(scale + col);
            float4 s1 = *reinterpret_cast<const float4*>(scale + col + 4);
            float4 t0 = *reinterpret_cast<const float4*>(shift + col);
            float4 t1 = *reinterpret_cast<const float4*>(shift + col + 4);
            v0.x = v0.x * s0.x + t0.x; v0.y = v0.y * s0.y + t0.y;
            v0.z = v0.z * s0.z + t0.z; v0.w = v0.w * s0.w + t0.w;
            v1.x = v1.x * s1.x + t1.x; v1.y = v1.y * s1.y + t1.y;
            v1.z = v1.z * s1.z + t1.z; v1.w = v1.w * s1.w + t1.w;
        }
        o[0] = __float2bfloat16(v0.x); o[1] = __float2bfloat16(v0.y);
        o[2] = __float2bfloat16(v0.z); o[3] = __float2bfloat16(v0.w);
        o[4] = __float2bfloat16(v1.x); o[5] = __float2bfloat16(v1.y);
        o[6] = __float2bfloat16(v1.z); o[7] = __float2bfloat16(v1.w);
    } else {
        for (int j = 0; j < 8; ++j) o[j] = __float2bfloat16(0.f);
    }
    *reinterpret_cast<bf16x8*>(Xbf + e0) = *reinterpret_cast<bf16x8*>(o);
}

template <int FIN, int WOUT>
__global__ __launch_bounds__(256) void castw_kernel(const float* __restrict__ W,
                                                    __hip_bfloat16* __restrict__ WT) {
    int i = blockIdx.x * 256 + threadIdx.x;
    if (i >= FIN * WOUT) return;
    int c = i / FIN, k = i % FIN;
    WT[i] = __float2bfloat16(W[(size_t)k * WOUT + c]);
}

// ---------------------------------------------------------------- MFMA GEMM
// A:[NP][FIN] bf16, BT:[WOUT][FIN] bf16, Hbf:[NP][WOUT] bf16
template <int FIN, int WOUT>
__global__ __launch_bounds__(256) void mgemm_kernel(const __hip_bfloat16* __restrict__ A,
                                                    const __hip_bfloat16* __restrict__ BT,
                                                    __hip_bfloat16* __restrict__ Hbf) {
    __shared__ __hip_bfloat16 As[128 * 32];
    __shared__ __hip_bfloat16 Bs[128 * 32];
    int t = threadIdx.x;
    int lane = t & 63, w = t >> 6;
    int row0 = blockIdx.x * 128;
    int col0 = blockIdx.y * 128;
    int wr = w >> 1, wc = w & 1;

    f32x4 acc[4][4];
    #pragma unroll
    for (int m = 0; m < 4; ++m)
        #pragma unroll
        for (int n = 0; n < 4; ++n) acc[m][n] = (f32x4){0.f, 0.f, 0.f, 0.f};

    int srow = w * 32 + (lane >> 2);
    int sbc  = (lane & 3) * 8;
    const __hip_bfloat16* gA0 = A  + (size_t)(row0 + srow)      * FIN + sbc;
    const __hip_bfloat16* gA1 = A  + (size_t)(row0 + srow + 16) * FIN + sbc;
    const __hip_bfloat16* gB0 = BT + (size_t)(col0 + srow)      * FIN + sbc;
    const __hip_bfloat16* gB1 = BT + (size_t)(col0 + srow + 16) * FIN + sbc;
    __hip_bfloat16* lA0 = As + w * 1024;
    __hip_bfloat16* lA1 = As + w * 1024 + 512;
    __hip_bfloat16* lB0 = Bs + w * 1024;
    __hip_bfloat16* lB1 = Bs + w * 1024 + 512;

    int rA = (wr * 64 + (lane & 15)) * 32 + (lane >> 4) * 8;
    int rB = (wc * 64 + (lane & 15)) * 32 + (lane >> 4) * 8;

    for (int k0 = 0; k0 < FIN; k0 += 32) {
        gload16(gA0 + k0, lA0);
        gload16(gA1 + k0, lA1);
        gload16(gB0 + k0, lB0);
        gload16(gB1 + k0, lB1);
        __syncthreads();
        bf16x8 af[4], bfr[4];
        #pragma unroll
        for (int m = 0; m < 4; ++m) af[m]  = *reinterpret_cast<const bf16x8*>(As + rA + m * 16 * 32);
        #pragma unroll
        for (int n = 0; n < 4; ++n) bfr[n] = *reinterpret_cast<const bf16x8*>(Bs + rB + n * 16 * 32);
        #pragma unroll
        for (int m = 0; m < 4; ++m)
            #pragma unroll
            for (int n = 0; n < 4; ++n)
                acc[m][n] = __builtin_amdgcn_mfma_f32_16x16x32_bf16(af[m], bfr[n], acc[m][n], 0, 0, 0);
        __syncthreads();
    }

    #pragma unroll
    for (int m = 0; m < 4; ++m) {
        #pragma unroll
        for (int n = 0; n < 4; ++n) {
            int r = row0 + wr * 64 + m * 16 + (lane >> 4) * 4;
            int c = col0 + wc * 64 + n * 16 + (lane & 15);
            #pragma unroll
            for (int j = 0; j < 4; ++j)
                Hbf[(size_t)(r + j) * WOUT + c] = __float2bfloat16(acc[m][n][j]);
        }
    }
}

// ---------------------------------------------------------------- per-node attention logits
template <int HC>
__global__ __launch_bounds__(256) void alsd_kernel(const __hip_bfloat16* __restrict__ Hm,
                                                   const float* __restrict__ a_src,
                                                   const float* __restrict__ a_dst,
                                                   float* __restrict__ als,
                                                   float* __restrict__ ald) {
    constexpr int VW = HC / 64;
    int wid  = threadIdx.x >> 6;
    int lane = threadIdx.x & 63;
    int node = blockIdx.x * 4 + wid;

    float ssum = 0.f, dsum = 0.f;
    if constexpr (VW == 4) {
        ushort4 h4 = *reinterpret_cast<const ushort4*>(Hm + (size_t)node * HC + lane * 4);
        float4 as = *reinterpret_cast<const float4*>(a_src + lane * 4);
        float4 ad = *reinterpret_cast<const float4*>(a_dst + lane * 4);
        float hx = bf2f(h4.x), hy = bf2f(h4.y), hz = bf2f(h4.z), hw = bf2f(h4.w);
        ssum = hx*as.x + hy*as.y + hz*as.z + hw*as.w;
        dsum = hx*ad.x + hy*ad.y + hz*ad.z + hw*ad.w;
    } else {
        ushort2 h2 = *reinterpret_cast<const ushort2*>(Hm + (size_t)node * HC + lane * 2);
        float2 as = *reinterpret_cast<const float2*>(a_src + lane * 2);
        float2 ad = *reinterpret_cast<const float2*>(a_dst + lane * 2);
        float hx = bf2f(h2.x), hy = bf2f(h2.y);
        ssum = hx*as.x + hy*as.y;
        dsum = hx*ad.x + hy*ad.y;
    }
    #pragma unroll
    for (int o = 1; o < 16; o <<= 1) {
        ssum += __shfl_xor(ssum, o);
        dsum += __shfl_xor(dsum, o);
    }
    if ((lane & 15) == 0) {
        int hd = lane >> 4;
        als[node * 4 + hd] = ssum;
        ald[node * 4 + hd] = dsum;
    }
}

// ---------------------------------------------------------------- fused one-pass edge softmax + aggregate
// One wave per destination; 4 groups of 16 lanes each own one edge in flight.
// Lane (group g, sublane q) accumulates columns [q*CPL, q*CPL+CPL).
// out = (sum_j w_j * h[src_j]) / (sum_j w_j),  w_j = exp(leaky_relu(als+ald))
template <int HC>
__global__ __launch_bounds__(256) void attn_kernel(const __hip_bfloat16* __restrict__ Hm,
                                                   const int* __restrict__ off,
                                                   const int* __restrict__ ssrc,
                                                   const float* __restrict__ als,
                                                   const float* __restrict__ ald,
                                                   const float* __restrict__ bias,
                                                   float* __restrict__ Out) {
    constexpr int CPL = HC / 16;           // cols per lane: 16 (HC=256) or 8 (HC=128)
    int wid  = threadIdx.x >> 6;
    int lane = threadIdx.x & 63;
    int d    = blockIdx.x * 4 + wid;
    int g    = lane >> 4;                  // edge group 0..3
    int q    = lane & 15;                  // sublane -> column segment
    int head = q >> 2;                     // CPL cols always within one head

    int e0 = off[d], e1 = off[d + 1];
    float aldh = ald[(size_t)d * 4 + head];

    float acc[CPL];
    #pragma unroll
    for (int c = 0; c < CPL; ++c) acc[c] = 0.f;
    float den = 0.f;

    for (int j = e0 + g; j < e1; j += 4) {
        int src = ssrc[j];
        float e = als[(size_t)src * 4 + head] + aldh;
        e = (e > 0.f) ? e : SLOPE * e;
        float wgt = __expf(e);
        den += wgt;
        const __hip_bfloat16* hp = Hm + (size_t)src * HC + q * CPL;
        if constexpr (CPL == 16) {
            bf16x8 v0 = *reinterpret_cast<const bf16x8*>(hp);
            bf16x8 v1 = *reinterpret_cast<const bf16x8*>(hp + 8);
            #pragma unroll
            for (int c = 0; c < 8; ++c) acc[c]     += wgt * bf2f((unsigned short)v0[c]);
            #pragma unroll
            for (int c = 0; c < 8; ++c) acc[8 + c] += wgt * bf2f((unsigned short)v1[c]);
        } else {
            bf16x8 v0 = *reinterpret_cast<const bf16x8*>(hp);
            #pragma unroll
            for (int c = 0; c < 8; ++c) acc[c] += wgt * bf2f((unsigned short)v0[c]);
        }
    }

    // reduce the 4 edge-groups (lanes q, q+16, q+32, q+48 hold same columns)
    #pragma unroll
    for (int c = 0; c < CPL; ++c) {
        acc[c] += __shfl_xor(acc[c], 16);
        acc[c] += __shfl_xor(acc[c], 32);
    }
    den += __shfl_xor(den, 16);
    den += __shfl_xor(den, 32);
    float inv = 1.f / (den + 1e-16f);

    if (g == 0) {
        #pragma unroll
        for (int c4 = 0; c4 < CPL / 4; ++c4) {
            float4 b4 = *reinterpret_cast<const float4*>(bias + q * CPL + c4 * 4);
            float4 o;
            o.x = fmaxf(acc[c4 * 4 + 0] * inv + b4.x, 0.f);
            o.y = fmaxf(acc[c4 * 4 + 1] * inv + b4.y, 0.f);
            o.z = fmaxf(acc[c4 * 4 + 2] * inv + b4.z, 0.f);
            o.w = fmaxf(acc[c4 * 4 + 3] * inv + b4.w, 0.f);
            *reinterpret_cast<float4*>(Out + (size_t)d * HC + q * CPL + c4 * 4) = o;
        }
    }
}

// ---------------------------------------------------------------- batch norm
__global__ __launch_bounds__(256) void bnstats_kernel(const float* __restrict__ X,
                                                      float* __restrict__ sums) {
    int c  = threadIdx.x;
    int r0 = blockIdx.x * 200;
    float s = 0.f, q = 0.f;
    for (int r = r0; r < r0 + 200; ++r) {
        float v = X[(size_t)r * 256 + c];
        s += v; q += v * v;
    }
    atomicAdd(&sums[c], s);
    atomicAdd(&sums[256 + c], q);
}

__global__ __launch_bounds__(256) void bnfinal_kernel(const float* __restrict__ sums,
                                                      const float* __restrict__ gamma,
                                                      const float* __restrict__ beta,
                                                      float* __restrict__ scale,
                                                      float* __restrict__ shift) {
    int c = threadIdx.x;
    float mean = sums[c] / (float)NN;
    float var  = sums[256 + c] / (float)NN - mean * mean;
    float inv  = rsqrtf(var + EPS_BN);
    float sc   = gamma[c] * inv;
    scale[c] = sc;
    shift[c] = beta[c] - mean * sc;
}

// ---------------------------------------------------------------- launch

extern "C" void kernel_launch(void* const* d_in, const int* in_sizes, int n_in,
                              void* d_out, int out_size, void* d_ws, size_t ws_size,
                              hipStream_t stream) {
    const float* x      = (const float*)d_in[0];
    const int*   ei     = (const int*)d_in[1];
    const float* W1     = (const float*)d_in[2];
    const float* a_s1   = (const float*)d_in[3];
    const float* a_d1   = (const float*)d_in[4];
    const float* b1     = (const float*)d_in[5];
    const float* W2     = (const float*)d_in[6];
    const float* a_s2   = (const float*)d_in[7];
    const float* a_d2   = (const float*)d_in[8];
    const float* b2     = (const float*)d_in[9];
    const float* W3     = (const float*)d_in[10];
    const float* a_s3   = (const float*)d_in[11];
    const float* a_d3   = (const float*)d_in[12];
    const float* b3     = (const float*)d_in[13];
    const float* gamma1 = (const float*)d_in[14];
    const float* beta1  = (const float*)d_in[15];
    const float* gamma2 = (const float*)d_in[16];
    const float* beta2  = (const float*)d_in[17];

    char* ws = (char*)d_ws;
    size_t o = 0;
    auto alloc = [&](size_t bytes) -> void* {
        void* p = ws + o;
        o = (o + bytes + 255) & ~size_t(255);
        return p;
    };
    float*           bufB = (float*)alloc((size_t)NN * 256 * 4);
    __hip_bfloat16*  Xbf  = (__hip_bfloat16*)alloc((size_t)NP * 256 * 2);
    __hip_bfloat16*  Hbf  = (__hip_bfloat16*)alloc((size_t)NP * 256 * 2);
    __hip_bfloat16*  WT   = (__hip_bfloat16*)alloc((size_t)256 * 256 * 2);
    float* als   = (float*)alloc((size_t)NN * 4 * 4);
    float* ald   = (float*)alloc((size_t)NN * 4 * 4);
    float* sums  = (float*)alloc(512 * 4);
    float* scale = (float*)alloc(256 * 4);
    float* shift = (float*)alloc(256 * 4);
    int*   off   = (int*)alloc((size_t)(NN + 1) * 4);
    int*   cur   = (int*)alloc((size_t)NN * 4);
    int*   cnt   = (int*)alloc((size_t)NN * 4);
    int*   ssrc  = (int*)alloc((size_t)ETOT * 4);
    (void)ws_size; (void)in_sizes; (void)n_in; (void)out_size;

    const int EB = (ETOT + 255) / 256;

    // --- CSR build (shared by all 3 layers)
    hipMemsetAsync(cnt, 0, (size_t)NN * 4, stream);
    count_kernel<<<EB, 256, 0, stream>>>(ei, cnt);
    scan_kernel<<<1, 1024, 0, stream>>>(cnt, off);
    hipMemcpyAsync(cur, off, (size_t)NN * 4, hipMemcpyDeviceToDevice, stream);
    fill_kernel<<<EB, 256, 0, stream>>>(ei, cur, ssrc);

    // --- layer 1
    cast_kernel<128, false><<<(int)(((long)NP * 128 / 8 + 255) / 256), 256, 0, stream>>>(x, nullptr, nullptr, Xbf);
    castw_kernel<128, 256><<<(128 * 256 + 255) / 256, 256, 0, stream>>>(W1, WT);
    mgemm_kernel<128, 256><<<dim3(NP / 128, 2), 256, 0, stream>>>(Xbf, WT, Hbf);
    alsd_kernel<256><<<NN / 4, 256, 0, stream>>>(Hbf, a_s1, a_d1, als, ald);
    attn_kernel<256><<<NN / 4, 256, 0, stream>>>(Hbf, off, ssrc, als, ald, b1, bufB);

    hipMemsetAsync(sums, 0, 512 * 4, stream);
    bnstats_kernel<<<250, 256, 0, stream>>>(bufB, sums);
    bnfinal_kernel<<<1, 256, 0, stream>>>(sums, gamma1, beta1, scale, shift);

    // --- layer 2
    cast_kernel<256, true><<<(int)(((long)NP * 256 / 8 + 255) / 256), 256, 0, stream>>>(bufB, scale, shift, Xbf);
    castw_kernel<256, 256><<<(256 * 256 + 255) / 256, 256, 0, stream>>>(W2, WT);
    mgemm_kernel<256, 256><<<dim3(NP / 128, 2), 256, 0, stream>>>(Xbf, WT, Hbf);
    alsd_kernel<256><<<NN / 4, 256, 0, stream>>>(Hbf, a_s2, a_d2, als, ald);
    attn_kernel<256><<<NN / 4, 256, 0, stream>>>(Hbf, off, ssrc, als, ald, b2, bufB);

    hipMemsetAsync(sums, 0, 512 * 4, stream);
    bnstats_kernel<<<250, 256, 0, stream>>>(bufB, sums);
    bnfinal_kernel<<<1, 256, 0, stream>>>(sums, gamma2, beta2, scale, shift);

    // --- layer 3
    cast_kernel<256, true><<<(int)(((long)NP * 256 / 8 + 255) / 256), 256, 0, stream>>>(bufB, scale, shift, Xbf);
    castw_kernel<256, 128><<<(256 * 128 + 255) / 256, 256, 0, stream>>>(W3, WT);
    mgemm_kernel<256, 128><<<dim3(NP / 128, 1), 256, 0, stream>>>(Xbf, WT, Hbf);
    alsd_kernel<128><<<NN / 4, 256, 0, stream>>>(Hbf, a_s3, a_d3, als, ald);
    attn_kernel<128><<<NN / 4, 256, 0, stream>>>(Hbf, off, ssrc, als, ald, b3, (float*)d_out);
}

// Round 4
// 413.646 us; speedup vs baseline: 2.6116x; 1.1835x over previous
//
#include <hip/hip_runtime.h>
#include <hip/hip_bf16.h>

// Problem constants (fixed by the reference)
constexpr int NN   = 50000;            // nodes
constexpr int EE   = 800000;           // random edges
constexpr int ETOT = EE + NN;          // + self loops
constexpr int NP   = 50048;            // rows padded to multiple of 128 (391*128)
constexpr int NBLK = (NN + 255) / 256; // 196 scan blocks
constexpr float SLOPE  = 0.2f;
constexpr float EPS_BN = 1e-5f;

typedef __attribute__((ext_vector_type(8))) short bf16x8;
typedef __attribute__((ext_vector_type(4))) float f32x4;

__device__ inline float bf2f(unsigned short u) {
    union { unsigned int i; float f; } c; c.i = ((unsigned int)u) << 16; return c.f;
}

__device__ inline void gload16(const __hip_bfloat16* g, __hip_bfloat16* l) {
    __builtin_amdgcn_global_load_lds(
        (const __attribute__((address_space(1))) unsigned int*)g,
        (__attribute__((address_space(3))) unsigned int*)l, 16, 0, 0);
}

// ---------------------------------------------------------------- CSR build

__global__ __launch_bounds__(256) void count_kernel(const int* __restrict__ ei,
                                                    int* __restrict__ cnt) {
    int j = blockIdx.x * 256 + threadIdx.x;
    if (j >= ETOT) return;
    int dst = (j < EE) ? ei[EE + j] : (j - EE);
    atomicAdd(&cnt[dst], 1);
}

// split scan: A) per-block scan, B) block-sum scan, C) add back (+ cur copy)
__global__ __launch_bounds__(256) void scanA_kernel(const int* __restrict__ cnt,
                                                    int* __restrict__ off,
                                                    int* __restrict__ bsum) {
    int b = blockIdx.x, t = threadIdx.x;
    int i = b * 256 + t;
    int v = (i < NN) ? cnt[i] : 0;
    int lane = t & 63, w = t >> 6;
    int x = v;
    #pragma unroll
    for (int o = 1; o < 64; o <<= 1) { int y = __shfl_up(x, o); if (lane >= o) x += y; }
    __shared__ int ws[4];
    if (lane == 63) ws[w] = x;
    __syncthreads();
    int wo = 0;
    for (int k = 0; k < w; ++k) wo += ws[k];
    int incl = x + wo;
    if (i < NN) off[i] = incl - v;       // block-local exclusive
    if (t == 255) bsum[b] = incl;
}

__global__ __launch_bounds__(256) void scanB_kernel(const int* __restrict__ bsum,
                                                    int* __restrict__ bexc,
                                                    int* __restrict__ off) {
    int t = threadIdx.x;
    int v = (t < NBLK) ? bsum[t] : 0;
    int lane = t & 63, w = t >> 6;
    int x = v;
    #pragma unroll
    for (int o = 1; o < 64; o <<= 1) { int y = __shfl_up(x, o); if (lane >= o) x += y; }
    __shared__ int ws[4];
    if (lane == 63) ws[w] = x;
    __syncthreads();
    int wo = 0;
    for (int k = 0; k < w; ++k) wo += ws[k];
    int incl = x + wo;
    if (t < NBLK) bexc[t] = incl - v;
    if (t == 255) off[NN] = incl;        // grand total
}

__global__ __launch_bounds__(256) void scanC_kernel(const int* __restrict__ bexc,
                                                    int* __restrict__ off,
                                                    int* __restrict__ cur) {
    int i = blockIdx.x * 256 + threadIdx.x;
    if (i >= NN) return;
    int v = off[i] + bexc[blockIdx.x];
    off[i] = v;
    cur[i] = v;
}

__global__ __launch_bounds__(256) void fill_kernel(const int* __restrict__ ei,
                                                   int* __restrict__ cursor,
                                                   int* __restrict__ ssrc) {
    int j = blockIdx.x * 256 + threadIdx.x;
    if (j >= ETOT) return;
    int src, dst;
    if (j < EE) { src = ei[j]; dst = ei[EE + j]; }
    else        { src = dst = j - EE; }
    int pos = atomicAdd(&cursor[dst], 1);
    ssrc[pos] = src;
}

// ---------------------------------------------------------------- casts
template <int F, bool BN>
__global__ __launch_bounds__(256) void cast_kernel(const float* __restrict__ X,
                                                   const float* __restrict__ scale,
                                                   const float* __restrict__ shift,
                                                   __hip_bfloat16* __restrict__ Xbf) {
    long idx = (long)blockIdx.x * 256 + threadIdx.x;     // 8 elems per thread
    long e0 = idx * 8;
    if (e0 >= (long)NP * F) return;
    int row = (int)(e0 / F);
    int col = (int)(e0 % F);
    __hip_bfloat16 o[8];
    if (row < NN) {
        float4 v0 = *reinterpret_cast<const float4*>(X + (size_t)row * F + col);
        float4 v1 = *reinterpret_cast<const float4*>(X + (size_t)row * F + col + 4);
        if (BN) {
            float4 s0 = *reinterpret_cast<const float4*>(scale + col);
            float4 s1 = *reinterpret_cast<const float4*>(scale + col + 4);
            float4 t0 = *reinterpret_cast<const float4*>(shift + col);
            float4 t1 = *reinterpret_cast<const float4*>(shift + col + 4);
            v0.x = v0.x * s0.x + t0.x; v0.y = v0.y * s0.y + t0.y;
            v0.z = v0.z * s0.z + t0.z; v0.w = v0.w * s0.w + t0.w;
            v1.x = v1.x * s1.x + t1.x; v1.y = v1.y * s1.y + t1.y;
            v1.z = v1.z * s1.z + t1.z; v1.w = v1.w * s1.w + t1.w;
        }
        o[0] = __float2bfloat16(v0.x); o[1] = __float2bfloat16(v0.y);
        o[2] = __float2bfloat16(v0.z); o[3] = __float2bfloat16(v0.w);
        o[4] = __float2bfloat16(v1.x); o[5] = __float2bfloat16(v1.y);
        o[6] = __float2bfloat16(v1.z); o[7] = __float2bfloat16(v1.w);
    } else {
        for (int j = 0; j < 8; ++j) o[j] = __float2bfloat16(0.f);
    }
    *reinterpret_cast<bf16x8*>(Xbf + e0) = *reinterpret_cast<bf16x8*>(o);
}

// all three W transposes in one launch (W:[FIN][WOUT] f32 -> WT:[WOUT][FIN] bf16)
__global__ __launch_bounds__(256) void castw_all_kernel(const float* __restrict__ W1,
                                                        const float* __restrict__ W2,
                                                        const float* __restrict__ W3,
                                                        __hip_bfloat16* __restrict__ WT1,
                                                        __hip_bfloat16* __restrict__ WT2,
                                                        __hip_bfloat16* __restrict__ WT3) {
    int i = blockIdx.x * 256 + threadIdx.x;
    if (i < 32768) {                       // W1: 128x256
        int c = i / 128, k = i % 128;
        WT1[i] = __float2bfloat16(W1[(size_t)k * 256 + c]);
    } else if (i < 98304) {                // W2: 256x256
        int j = i - 32768;
        int c = j / 256, k = j % 256;
        WT2[j] = __float2bfloat16(W2[(size_t)k * 256 + c]);
    } else if (i < 131072) {               // W3: 256x128
        int j = i - 98304;
        int c = j / 256, k = j % 256;
        WT3[j] = __float2bfloat16(W3[(size_t)k * 128 + c]);
    }
}

// ---------------------------------------------------------------- MFMA GEMM
template <int FIN, int WOUT>
__global__ __launch_bounds__(256) void mgemm_kernel(const __hip_bfloat16* __restrict__ A,
                                                    const __hip_bfloat16* __restrict__ BT,
                                                    __hip_bfloat16* __restrict__ Hbf) {
    __shared__ __hip_bfloat16 As[128 * 32];
    __shared__ __hip_bfloat16 Bs[128 * 32];
    int t = threadIdx.x;
    int lane = t & 63, w = t >> 6;
    int row0 = blockIdx.x * 128;
    int col0 = blockIdx.y * 128;
    int wr = w >> 1, wc = w & 1;

    f32x4 acc[4][4];
    #pragma unroll
    for (int m = 0; m < 4; ++m)
        #pragma unroll
        for (int n = 0; n < 4; ++n) acc[m][n] = (f32x4){0.f, 0.f, 0.f, 0.f};

    int srow = w * 32 + (lane >> 2);
    int sbc  = (lane & 3) * 8;
    const __hip_bfloat16* gA0 = A  + (size_t)(row0 + srow)      * FIN + sbc;
    const __hip_bfloat16* gA1 = A  + (size_t)(row0 + srow + 16) * FIN + sbc;
    const __hip_bfloat16* gB0 = BT + (size_t)(col0 + srow)      * FIN + sbc;
    const __hip_bfloat16* gB1 = BT + (size_t)(col0 + srow + 16) * FIN + sbc;
    __hip_bfloat16* lA0 = As + w * 1024;
    __hip_bfloat16* lA1 = As + w * 1024 + 512;
    __hip_bfloat16* lB0 = Bs + w * 1024;
    __hip_bfloat16* lB1 = Bs + w * 1024 + 512;

    int rA = (wr * 64 + (lane & 15)) * 32 + (lane >> 4) * 8;
    int rB = (wc * 64 + (lane & 15)) * 32 + (lane >> 4) * 8;

    for (int k0 = 0; k0 < FIN; k0 += 32) {
        gload16(gA0 + k0, lA0);
        gload16(gA1 + k0, lA1);
        gload16(gB0 + k0, lB0);
        gload16(gB1 + k0, lB1);
        __syncthreads();
        bf16x8 af[4], bfr[4];
        #pragma unroll
        for (int m = 0; m < 4; ++m) af[m]  = *reinterpret_cast<const bf16x8*>(As + rA + m * 16 * 32);
        #pragma unroll
        for (int n = 0; n < 4; ++n) bfr[n] = *reinterpret_cast<const bf16x8*>(Bs + rB + n * 16 * 32);
        #pragma unroll
        for (int m = 0; m < 4; ++m)
            #pragma unroll
            for (int n = 0; n < 4; ++n)
                acc[m][n] = __builtin_amdgcn_mfma_f32_16x16x32_bf16(af[m], bfr[n], acc[m][n], 0, 0, 0);
        __syncthreads();
    }

    #pragma unroll
    for (int m = 0; m < 4; ++m) {
        #pragma unroll
        for (int n = 0; n < 4; ++n) {
            int r = row0 + wr * 64 + m * 16 + (lane >> 4) * 4;
            int c = col0 + wc * 64 + n * 16 + (lane & 15);
            #pragma unroll
            for (int j = 0; j < 4; ++j)
                Hbf[(size_t)(r + j) * WOUT + c] = __float2bfloat16(acc[m][n][j]);
        }
    }
}

// ---------------------------------------------------------------- per-node attention logits
template <int HC>
__global__ __launch_bounds__(256) void alsd_kernel(const __hip_bfloat16* __restrict__ Hm,
                                                   const float* __restrict__ a_src,
                                                   const float* __restrict__ a_dst,
                                                   float* __restrict__ als,
                                                   float* __restrict__ ald) {
    constexpr int VW = HC / 64;
    int wid  = threadIdx.x >> 6;
    int lane = threadIdx.x & 63;
    int node = blockIdx.x * 4 + wid;

    float ssum = 0.f, dsum = 0.f;
    if constexpr (VW == 4) {
        ushort4 h4 = *reinterpret_cast<const ushort4*>(Hm + (size_t)node * HC + lane * 4);
        float4 as = *reinterpret_cast<const float4*>(a_src + lane * 4);
        float4 ad = *reinterpret_cast<const float4*>(a_dst + lane * 4);
        float hx = bf2f(h4.x), hy = bf2f(h4.y), hz = bf2f(h4.z), hw = bf2f(h4.w);
        ssum = hx*as.x + hy*as.y + hz*as.z + hw*as.w;
        dsum = hx*ad.x + hy*ad.y + hz*ad.z + hw*ad.w;
    } else {
        ushort2 h2 = *reinterpret_cast<const ushort2*>(Hm + (size_t)node * HC + lane * 2);
        float2 as = *reinterpret_cast<const float2*>(a_src + lane * 2);
        float2 ad = *reinterpret_cast<const float2*>(a_dst + lane * 2);
        float hx = bf2f(h2.x), hy = bf2f(h2.y);
        ssum = hx*as.x + hy*as.y;
        dsum = hx*ad.x + hy*ad.y;
    }
    #pragma unroll
    for (int o = 1; o < 16; o <<= 1) {
        ssum += __shfl_xor(ssum, o);
        dsum += __shfl_xor(dsum, o);
    }
    if ((lane & 15) == 0) {
        int hd = lane >> 4;
        als[node * 4 + hd] = ssum;
        ald[node * 4 + hd] = dsum;
    }
}

// ---------------------------------------------------------------- fused one-pass edge softmax + aggregate
template <int HC>
__global__ __launch_bounds__(256) void attn_kernel(const __hip_bfloat16* __restrict__ Hm,
                                                   const int* __restrict__ off,
                                                   const int* __restrict__ ssrc,
                                                   const float* __restrict__ als,
                                                   const float* __restrict__ ald,
                                                   const float* __restrict__ bias,
                                                   float* __restrict__ Out) {
    constexpr int CPL = HC / 16;           // cols per lane: 16 (HC=256) or 8 (HC=128)
    int wid  = threadIdx.x >> 6;
    int lane = threadIdx.x & 63;
    int d    = blockIdx.x * 4 + wid;
    int g    = lane >> 4;                  // edge group 0..3
    int q    = lane & 15;                  // sublane -> column segment
    int head = q >> 2;                     // CPL cols always within one head

    int e0 = off[d], e1 = off[d + 1];
    float aldh = ald[(size_t)d * 4 + head];

    float acc[CPL];
    #pragma unroll
    for (int c = 0; c < CPL; ++c) acc[c] = 0.f;
    float den = 0.f;

    for (int j = e0 + g; j < e1; j += 4) {
        int src = ssrc[j];
        float e = als[(size_t)src * 4 + head] + aldh;
        e = (e > 0.f) ? e : SLOPE * e;
        float wgt = __expf(e);
        den += wgt;
        const __hip_bfloat16* hp = Hm + (size_t)src * HC + q * CPL;
        if constexpr (CPL == 16) {
            bf16x8 v0 = *reinterpret_cast<const bf16x8*>(hp);
            bf16x8 v1 = *reinterpret_cast<const bf16x8*>(hp + 8);
            #pragma unroll
            for (int c = 0; c < 8; ++c) acc[c]     += wgt * bf2f((unsigned short)v0[c]);
            #pragma unroll
            for (int c = 0; c < 8; ++c) acc[8 + c] += wgt * bf2f((unsigned short)v1[c]);
        } else {
            bf16x8 v0 = *reinterpret_cast<const bf16x8*>(hp);
            #pragma unroll
            for (int c = 0; c < 8; ++c) acc[c] += wgt * bf2f((unsigned short)v0[c]);
        }
    }

    #pragma unroll
    for (int c = 0; c < CPL; ++c) {
        acc[c] += __shfl_xor(acc[c], 16);
        acc[c] += __shfl_xor(acc[c], 32);
    }
    den += __shfl_xor(den, 16);
    den += __shfl_xor(den, 32);
    float inv = 1.f / (den + 1e-16f);

    if (g == 0) {
        #pragma unroll
        for (int c4 = 0; c4 < CPL / 4; ++c4) {
            float4 b4 = *reinterpret_cast<const float4*>(bias + q * CPL + c4 * 4);
            float4 o;
            o.x = fmaxf(acc[c4 * 4 + 0] * inv + b4.x, 0.f);
            o.y = fmaxf(acc[c4 * 4 + 1] * inv + b4.y, 0.f);
            o.z = fmaxf(acc[c4 * 4 + 2] * inv + b4.z, 0.f);
            o.w = fmaxf(acc[c4 * 4 + 3] * inv + b4.w, 0.f);
            *reinterpret_cast<float4*>(Out + (size_t)d * HC + q * CPL + c4 * 4) = o;
        }
    }
}

// ---------------------------------------------------------------- batch norm
__global__ __launch_bounds__(256) void bnstats_kernel(const float* __restrict__ X,
                                                      float* __restrict__ sums) {
    int c  = threadIdx.x;
    int r0 = blockIdx.x * 200;
    float s = 0.f, q = 0.f;
    for (int r = r0; r < r0 + 200; ++r) {
        float v = X[(size_t)r * 256 + c];
        s += v; q += v * v;
    }
    atomicAdd(&sums[c], s);
    atomicAdd(&sums[256 + c], q);
}

__global__ __launch_bounds__(256) void bnfinal_kernel(const float* __restrict__ sums,
                                                      const float* __restrict__ gamma,
                                                      const float* __restrict__ beta,
                                                      float* __restrict__ scale,
                                                      float* __restrict__ shift) {
    int c = threadIdx.x;
    float mean = sums[c] / (float)NN;
    float var  = sums[256 + c] / (float)NN - mean * mean;
    float inv  = rsqrtf(var + EPS_BN);
    float sc   = gamma[c] * inv;
    scale[c] = sc;
    shift[c] = beta[c] - mean * sc;
}

// ---------------------------------------------------------------- launch

extern "C" void kernel_launch(void* const* d_in, const int* in_sizes, int n_in,
                              void* d_out, int out_size, void* d_ws, size_t ws_size,
                              hipStream_t stream) {
    const float* x      = (const float*)d_in[0];
    const int*   ei     = (const int*)d_in[1];
    const float* W1     = (const float*)d_in[2];
    const float* a_s1   = (const float*)d_in[3];
    const float* a_d1   = (const float*)d_in[4];
    const float* b1     = (const float*)d_in[5];
    const float* W2     = (const float*)d_in[6];
    const float* a_s2   = (const float*)d_in[7];
    const float* a_d2   = (const float*)d_in[8];
    const float* b2     = (const float*)d_in[9];
    const float* W3     = (const float*)d_in[10];
    const float* a_s3   = (const float*)d_in[11];
    const float* a_d3   = (const float*)d_in[12];
    const float* b3     = (const float*)d_in[13];
    const float* gamma1 = (const float*)d_in[14];
    const float* beta1  = (const float*)d_in[15];
    const float* gamma2 = (const float*)d_in[16];
    const float* beta2  = (const float*)d_in[17];

    char* ws = (char*)d_ws;
    size_t o = 0;
    auto alloc = [&](size_t bytes) -> void* {
        void* p = ws + o;
        o = (o + bytes + 255) & ~size_t(255);
        return p;
    };
    float*           bufB = (float*)alloc((size_t)NN * 256 * 4);
    __hip_bfloat16*  Xbf  = (__hip_bfloat16*)alloc((size_t)NP * 256 * 2);
    __hip_bfloat16*  Hbf  = (__hip_bfloat16*)alloc((size_t)NP * 256 * 2);
    __hip_bfloat16*  WT1  = (__hip_bfloat16*)alloc((size_t)256 * 128 * 2);
    __hip_bfloat16*  WT2  = (__hip_bfloat16*)alloc((size_t)256 * 256 * 2);
    __hip_bfloat16*  WT3  = (__hip_bfloat16*)alloc((size_t)128 * 256 * 2);
    float* als   = (float*)alloc((size_t)NN * 4 * 4);
    float* ald   = (float*)alloc((size_t)NN * 4 * 4);
    float* sums  = (float*)alloc(512 * 4);
    float* scale = (float*)alloc(256 * 4);
    float* shift = (float*)alloc(256 * 4);
    int*   off   = (int*)alloc((size_t)(NN + 1) * 4);
    int*   cur   = (int*)alloc((size_t)NN * 4);
    int*   cnt   = (int*)alloc((size_t)NN * 4);
    int*   bsum  = (int*)alloc((size_t)NBLK * 4);
    int*   bexc  = (int*)alloc((size_t)NBLK * 4);
    int*   ssrc  = (int*)alloc((size_t)ETOT * 4);
    (void)ws_size; (void)in_sizes; (void)n_in; (void)out_size;

    const int EB = (ETOT + 255) / 256;

    // --- CSR build (shared by all 3 layers)
    hipMemsetAsync(cnt, 0, (size_t)NN * 4, stream);
    count_kernel<<<EB, 256, 0, stream>>>(ei, cnt);
    scanA_kernel<<<NBLK, 256, 0, stream>>>(cnt, off, bsum);
    scanB_kernel<<<1, 256, 0, stream>>>(bsum, bexc, off);
    scanC_kernel<<<NBLK, 256, 0, stream>>>(bexc, off, cur);
    fill_kernel<<<EB, 256, 0, stream>>>(ei, cur, ssrc);

    // --- weights (all layers, once)
    castw_all_kernel<<<512, 256, 0, stream>>>(W1, W2, W3, WT1, WT2, WT3);

    // --- layer 1
    cast_kernel<128, false><<<(int)(((long)NP * 128 / 8 + 255) / 256), 256, 0, stream>>>(x, nullptr, nullptr, Xbf);
    mgemm_kernel<128, 256><<<dim3(NP / 128, 2), 256, 0, stream>>>(Xbf, WT1, Hbf);
    alsd_kernel<256><<<NN / 4, 256, 0, stream>>>(Hbf, a_s1, a_d1, als, ald);
    attn_kernel<256><<<NN / 4, 256, 0, stream>>>(Hbf, off, ssrc, als, ald, b1, bufB);

    hipMemsetAsync(sums, 0, 512 * 4, stream);
    bnstats_kernel<<<250, 256, 0, stream>>>(bufB, sums);
    bnfinal_kernel<<<1, 256, 0, stream>>>(sums, gamma1, beta1, scale, shift);

    // --- layer 2
    cast_kernel<256, true><<<(int)(((long)NP * 256 / 8 + 255) / 256), 256, 0, stream>>>(bufB, scale, shift, Xbf);
    mgemm_kernel<256, 256><<<dim3(NP / 128, 2), 256, 0, stream>>>(Xbf, WT2, Hbf);
    alsd_kernel<256><<<NN / 4, 256, 0, stream>>>(Hbf, a_s2, a_d2, als, ald);
    attn_kernel<256><<<NN / 4, 256, 0, stream>>>(Hbf, off, ssrc, als, ald, b2, bufB);

    hipMemsetAsync(sums, 0, 512 * 4, stream);
    bnstats_kernel<<<250, 256, 0, stream>>>(bufB, sums);
    bnfinal_kernel<<<1, 256, 0, stream>>>(sums, gamma2, beta2, scale, shift);

    // --- layer 3
    cast_kernel<256, true><<<(int)(((long)NP * 256 / 8 + 255) / 256), 256, 0, stream>>>(bufB, scale, shift, Xbf);
    mgemm_kernel<256, 128><<<dim3(NP / 128, 1), 256, 0, stream>>>(Xbf, WT3, Hbf);
    alsd_kernel<128><<<NN / 4, 256, 0, stream>>>(Hbf, a_s3, a_d3, als, ald);
    attn_kernel<128><<<NN / 4, 256, 0, stream>>>(Hbf, off, ssrc, als, ald, b3, (float*)d_out);
}

// Round 5
// 402.454 us; speedup vs baseline: 2.6842x; 1.0278x over previous
//
#include <hip/hip_runtime.h>
#include <hip/hip_bf16.h>

// Problem constants (fixed by the reference)
constexpr int NN   = 50000;            // nodes
constexpr int EE   = 800000;           // random edges
constexpr int ETOT = EE + NN;          // + self loops
constexpr int NP   = 50048;            // rows padded to multiple of 128 (391*128)
constexpr int NBLK = (NN + 255) / 256; // 196 scan blocks
constexpr float SLOPE  = 0.2f;
constexpr float EPS_BN = 1e-5f;

typedef __attribute__((ext_vector_type(8))) short bf16x8;
typedef __attribute__((ext_vector_type(4))) float f32x4;

__device__ inline float bf2f(unsigned short u) {
    union { unsigned int i; float f; } c; c.i = ((unsigned int)u) << 16; return c.f;
}

__device__ inline void gload16(const __hip_bfloat16* g, __hip_bfloat16* l) {
    __builtin_amdgcn_global_load_lds(
        (const __attribute__((address_space(1))) unsigned int*)g,
        (__attribute__((address_space(3))) unsigned int*)l, 16, 0, 0);
}

// ---------------------------------------------------------------- CSR build

__global__ __launch_bounds__(256) void count_kernel(const int* __restrict__ ei,
                                                    int* __restrict__ cnt) {
    int j = blockIdx.x * 256 + threadIdx.x;
    if (j >= ETOT) return;
    int dst = (j < EE) ? ei[EE + j] : (j - EE);
    atomicAdd(&cnt[dst], 1);
}

__global__ __launch_bounds__(256) void scanA_kernel(const int* __restrict__ cnt,
                                                    int* __restrict__ off,
                                                    int* __restrict__ bsum) {
    int b = blockIdx.x, t = threadIdx.x;
    int i = b * 256 + t;
    int v = (i < NN) ? cnt[i] : 0;
    int lane = t & 63, w = t >> 6;
    int x = v;
    #pragma unroll
    for (int o = 1; o < 64; o <<= 1) { int y = __shfl_up(x, o); if (lane >= o) x += y; }
    __shared__ int ws[4];
    if (lane == 63) ws[w] = x;
    __syncthreads();
    int wo = 0;
    for (int k = 0; k < w; ++k) wo += ws[k];
    int incl = x + wo;
    if (i < NN) off[i] = incl - v;
    if (t == 255) bsum[b] = incl;
}

__global__ __launch_bounds__(256) void scanB_kernel(const int* __restrict__ bsum,
                                                    int* __restrict__ bexc,
                                                    int* __restrict__ off) {
    int t = threadIdx.x;
    int v = (t < NBLK) ? bsum[t] : 0;
    int lane = t & 63, w = t >> 6;
    int x = v;
    #pragma unroll
    for (int o = 1; o < 64; o <<= 1) { int y = __shfl_up(x, o); if (lane >= o) x += y; }
    __shared__ int ws[4];
    if (lane == 63) ws[w] = x;
    __syncthreads();
    int wo = 0;
    for (int k = 0; k < w; ++k) wo += ws[k];
    int incl = x + wo;
    if (t < NBLK) bexc[t] = incl - v;
    if (t == 255) off[NN] = incl;
}

__global__ __launch_bounds__(256) void scanC_kernel(const int* __restrict__ bexc,
                                                    int* __restrict__ off,
                                                    int* __restrict__ cur) {
    int i = blockIdx.x * 256 + threadIdx.x;
    if (i >= NN) return;
    int v = off[i] + bexc[blockIdx.x];
    off[i] = v;
    cur[i] = v;
}

__global__ __launch_bounds__(256) void fill_kernel(const int* __restrict__ ei,
                                                   int* __restrict__ cursor,
                                                   int* __restrict__ ssrc) {
    int j = blockIdx.x * 256 + threadIdx.x;
    if (j >= ETOT) return;
    int src, dst;
    if (j < EE) { src = ei[j]; dst = ei[EE + j]; }
    else        { src = dst = j - EE; }
    int pos = atomicAdd(&cursor[dst], 1);
    ssrc[pos] = src;
}

// ---------------------------------------------------------------- casts
// x f32 [NN][128] -> Xbf [NP][128] bf16, pad rows zeroed
__global__ __launch_bounds__(256) void castx_kernel(const float* __restrict__ X,
                                                    __hip_bfloat16* __restrict__ Xbf) {
    long e0 = ((long)blockIdx.x * 256 + threadIdx.x) * 8;
    if (e0 >= (long)NP * 128) return;
    int row = (int)(e0 / 128);
    __hip_bfloat16 o[8];
    if (row < NN) {
        float4 v0 = *reinterpret_cast<const float4*>(X + e0);
        float4 v1 = *reinterpret_cast<const float4*>(X + e0 + 4);
        o[0] = __float2bfloat16(v0.x); o[1] = __float2bfloat16(v0.y);
        o[2] = __float2bfloat16(v0.z); o[3] = __float2bfloat16(v0.w);
        o[4] = __float2bfloat16(v1.x); o[5] = __float2bfloat16(v1.y);
        o[6] = __float2bfloat16(v1.z); o[7] = __float2bfloat16(v1.w);
    } else {
        for (int j = 0; j < 8; ++j) o[j] = __float2bfloat16(0.f);
    }
    *reinterpret_cast<bf16x8*>(Xbf + e0) = *reinterpret_cast<bf16x8*>(o);
}

// W1 [128][256] f32 -> WT1 [256][128] bf16
__global__ __launch_bounds__(256) void castw1_kernel(const float* __restrict__ W,
                                                     __hip_bfloat16* __restrict__ WT) {
    int i = blockIdx.x * 256 + threadIdx.x;
    if (i >= 32768) return;
    int c = i / 128, k = i % 128;
    WT[i] = __float2bfloat16(W[(size_t)k * 256 + c]);
}

// fold BN affine into next-layer weight: WT'[c][k] = bf16(scale[k]*W[k][c]);
// bb[c] = sum_k shift[k]*W[k][c]
template <int FIN, int WOUT>
__global__ __launch_bounds__(FIN) void foldw_kernel(const float* __restrict__ W,
                                                    const float* __restrict__ scale,
                                                    const float* __restrict__ shift,
                                                    __hip_bfloat16* __restrict__ WTp,
                                                    float* __restrict__ bb) {
    int c = blockIdx.x, k = threadIdx.x;
    float w = W[(size_t)k * WOUT + c];
    WTp[(size_t)c * FIN + k] = __float2bfloat16(scale[k] * w);
    float p = shift[k] * w;
    #pragma unroll
    for (int o = 1; o < 64; o <<= 1) p += __shfl_xor(p, o);
    __shared__ float ps[FIN / 64];
    if ((k & 63) == 0) ps[k >> 6] = p;
    __syncthreads();
    if (k == 0) {
        float s = 0.f;
        #pragma unroll
        for (int q = 0; q < FIN / 64; ++q) s += ps[q];
        bb[c] = s;
    }
}

// ---------------------------------------------------------------- MFMA GEMM
// A:[NP][FIN] bf16, BT:[WOUT][FIN] bf16, Hbf:[NP][WOUT] bf16 (+= bb[c] if FOLD)
template <int FIN, int WOUT, bool FOLD>
__global__ __launch_bounds__(256) void mgemm_kernel(const __hip_bfloat16* __restrict__ A,
                                                    const __hip_bfloat16* __restrict__ BT,
                                                    const float* __restrict__ bb,
                                                    __hip_bfloat16* __restrict__ Hbf) {
    __shared__ __hip_bfloat16 As[128 * 32];
    __shared__ __hip_bfloat16 Bs[128 * 32];
    int t = threadIdx.x;
    int lane = t & 63, w = t >> 6;
    int row0 = blockIdx.x * 128;
    int col0 = blockIdx.y * 128;
    int wr = w >> 1, wc = w & 1;

    f32x4 acc[4][4];
    #pragma unroll
    for (int m = 0; m < 4; ++m)
        #pragma unroll
        for (int n = 0; n < 4; ++n) acc[m][n] = (f32x4){0.f, 0.f, 0.f, 0.f};

    int srow = w * 32 + (lane >> 2);
    int sbc  = (lane & 3) * 8;
    const __hip_bfloat16* gA0 = A  + (size_t)(row0 + srow)      * FIN + sbc;
    const __hip_bfloat16* gA1 = A  + (size_t)(row0 + srow + 16) * FIN + sbc;
    const __hip_bfloat16* gB0 = BT + (size_t)(col0 + srow)      * FIN + sbc;
    const __hip_bfloat16* gB1 = BT + (size_t)(col0 + srow + 16) * FIN + sbc;
    __hip_bfloat16* lA0 = As + w * 1024;
    __hip_bfloat16* lA1 = As + w * 1024 + 512;
    __hip_bfloat16* lB0 = Bs + w * 1024;
    __hip_bfloat16* lB1 = Bs + w * 1024 + 512;

    int rA = (wr * 64 + (lane & 15)) * 32 + (lane >> 4) * 8;
    int rB = (wc * 64 + (lane & 15)) * 32 + (lane >> 4) * 8;

    for (int k0 = 0; k0 < FIN; k0 += 32) {
        gload16(gA0 + k0, lA0);
        gload16(gA1 + k0, lA1);
        gload16(gB0 + k0, lB0);
        gload16(gB1 + k0, lB1);
        __syncthreads();
        bf16x8 af[4], bfr[4];
        #pragma unroll
        for (int m = 0; m < 4; ++m) af[m]  = *reinterpret_cast<const bf16x8*>(As + rA + m * 16 * 32);
        #pragma unroll
        for (int n = 0; n < 4; ++n) bfr[n] = *reinterpret_cast<const bf16x8*>(Bs + rB + n * 16 * 32);
        #pragma unroll
        for (int m = 0; m < 4; ++m)
            #pragma unroll
            for (int n = 0; n < 4; ++n)
                acc[m][n] = __builtin_amdgcn_mfma_f32_16x16x32_bf16(af[m], bfr[n], acc[m][n], 0, 0, 0);
        __syncthreads();
    }

    #pragma unroll
    for (int n = 0; n < 4; ++n) {
        int c = col0 + wc * 64 + n * 16 + (lane & 15);
        float badd = FOLD ? bb[c] : 0.f;
        #pragma unroll
        for (int m = 0; m < 4; ++m) {
            int r = row0 + wr * 64 + m * 16 + (lane >> 4) * 4;
            #pragma unroll
            for (int j = 0; j < 4; ++j)
                Hbf[(size_t)(r + j) * WOUT + c] = __float2bfloat16(acc[m][n][j] + badd);
        }
    }
}

// ---------------------------------------------------------------- per-node attention logits
template <int HC>
__global__ __launch_bounds__(256) void alsd_kernel(const __hip_bfloat16* __restrict__ Hm,
                                                   const float* __restrict__ a_src,
                                                   const float* __restrict__ a_dst,
                                                   float* __restrict__ als,
                                                   float* __restrict__ ald) {
    constexpr int VW = HC / 64;
    int wid  = threadIdx.x >> 6;
    int lane = threadIdx.x & 63;
    int node = blockIdx.x * 4 + wid;

    float ssum = 0.f, dsum = 0.f;
    if constexpr (VW == 4) {
        ushort4 h4 = *reinterpret_cast<const ushort4*>(Hm + (size_t)node * HC + lane * 4);
        float4 as = *reinterpret_cast<const float4*>(a_src + lane * 4);
        float4 ad = *reinterpret_cast<const float4*>(a_dst + lane * 4);
        float hx = bf2f(h4.x), hy = bf2f(h4.y), hz = bf2f(h4.z), hw = bf2f(h4.w);
        ssum = hx*as.x + hy*as.y + hz*as.z + hw*as.w;
        dsum = hx*ad.x + hy*ad.y + hz*ad.z + hw*ad.w;
    } else {
        ushort2 h2 = *reinterpret_cast<const ushort2*>(Hm + (size_t)node * HC + lane * 2);
        float2 as = *reinterpret_cast<const float2*>(a_src + lane * 2);
        float2 ad = *reinterpret_cast<const float2*>(a_dst + lane * 2);
        float hx = bf2f(h2.x), hy = bf2f(h2.y);
        ssum = hx*as.x + hy*as.y;
        dsum = hx*ad.x + hy*ad.y;
    }
    #pragma unroll
    for (int o = 1; o < 16; o <<= 1) {
        ssum += __shfl_xor(ssum, o);
        dsum += __shfl_xor(dsum, o);
    }
    if ((lane & 15) == 0) {
        int hd = lane >> 4;
        als[node * 4 + hd] = ssum;
        ald[node * 4 + hd] = dsum;
    }
}

// ---------------------------------------------------------------- fused one-pass edge softmax + aggregate
// 4 groups x 16 lanes; 2x unrolled (8 edges in flight per wave).
// OUTBF: write bf16 (layers 1,2); else f32 (final layer).
template <int HC, bool OUTBF>
__global__ __launch_bounds__(256) void attn_kernel(const __hip_bfloat16* __restrict__ Hm,
                                                   const int* __restrict__ off,
                                                   const int* __restrict__ ssrc,
                                                   const float* __restrict__ als,
                                                   const float* __restrict__ ald,
                                                   const float* __restrict__ bias,
                                                   void* __restrict__ Outv) {
    constexpr int CPL = HC / 16;           // 16 (HC=256) or 8 (HC=128)
    int wid  = threadIdx.x >> 6;
    int lane = threadIdx.x & 63;
    int d    = blockIdx.x * 4 + wid;
    int g    = lane >> 4;
    int q    = lane & 15;
    int head = q >> 2;

    int e0 = off[d], e1 = off[d + 1];
    float aldh = ald[(size_t)d * 4 + head];

    float acc0[CPL], acc1[CPL];
    #pragma unroll
    for (int c = 0; c < CPL; ++c) { acc0[c] = 0.f; acc1[c] = 0.f; }
    float den0 = 0.f, den1 = 0.f;

    int j = e0 + g;
    for (; j + 4 < e1; j += 8) {
        int s0 = ssrc[j];
        int s1 = ssrc[j + 4];
        float ea = als[(size_t)s0 * 4 + head] + aldh;
        ea = (ea > 0.f) ? ea : SLOPE * ea;
        float eb = als[(size_t)s1 * 4 + head] + aldh;
        eb = (eb > 0.f) ? eb : SLOPE * eb;
        float w0 = __expf(ea), w1 = __expf(eb);
        den0 += w0; den1 += w1;
        const __hip_bfloat16* hp0 = Hm + (size_t)s0 * HC + q * CPL;
        const __hip_bfloat16* hp1 = Hm + (size_t)s1 * HC + q * CPL;
        if constexpr (CPL == 16) {
            bf16x8 a0 = *reinterpret_cast<const bf16x8*>(hp0);
            bf16x8 a1 = *reinterpret_cast<const bf16x8*>(hp0 + 8);
            bf16x8 b0 = *reinterpret_cast<const bf16x8*>(hp1);
            bf16x8 b1 = *reinterpret_cast<const bf16x8*>(hp1 + 8);
            #pragma unroll
            for (int c = 0; c < 8; ++c) {
                acc0[c]     += w0 * bf2f((unsigned short)a0[c]);
                acc0[8 + c] += w0 * bf2f((unsigned short)a1[c]);
                acc1[c]     += w1 * bf2f((unsigned short)b0[c]);
                acc1[8 + c] += w1 * bf2f((unsigned short)b1[c]);
            }
        } else {
            bf16x8 a0 = *reinterpret_cast<const bf16x8*>(hp0);
            bf16x8 b0 = *reinterpret_cast<const bf16x8*>(hp1);
            #pragma unroll
            for (int c = 0; c < 8; ++c) {
                acc0[c] += w0 * bf2f((unsigned short)a0[c]);
                acc1[c] += w1 * bf2f((unsigned short)b0[c]);
            }
        }
    }
    if (j < e1) {
        int s0 = ssrc[j];
        float ea = als[(size_t)s0 * 4 + head] + aldh;
        ea = (ea > 0.f) ? ea : SLOPE * ea;
        float w0 = __expf(ea);
        den0 += w0;
        const __hip_bfloat16* hp0 = Hm + (size_t)s0 * HC + q * CPL;
        if constexpr (CPL == 16) {
            bf16x8 a0 = *reinterpret_cast<const bf16x8*>(hp0);
            bf16x8 a1 = *reinterpret_cast<const bf16x8*>(hp0 + 8);
            #pragma unroll
            for (int c = 0; c < 8; ++c) {
                acc0[c]     += w0 * bf2f((unsigned short)a0[c]);
                acc0[8 + c] += w0 * bf2f((unsigned short)a1[c]);
            }
        } else {
            bf16x8 a0 = *reinterpret_cast<const bf16x8*>(hp0);
            #pragma unroll
            for (int c = 0; c < 8; ++c) acc0[c] += w0 * bf2f((unsigned short)a0[c]);
        }
    }

    float den = den0 + den1;
    float acc[CPL];
    #pragma unroll
    for (int c = 0; c < CPL; ++c) acc[c] = acc0[c] + acc1[c];

    #pragma unroll
    for (int c = 0; c < CPL; ++c) {
        acc[c] += __shfl_xor(acc[c], 16);
        acc[c] += __shfl_xor(acc[c], 32);
    }
    den += __shfl_xor(den, 16);
    den += __shfl_xor(den, 32);
    float inv = 1.f / (den + 1e-16f);

    if (g == 0) {
        float o[CPL];
        #pragma unroll
        for (int c4 = 0; c4 < CPL / 4; ++c4) {
            float4 b4 = *reinterpret_cast<const float4*>(bias + q * CPL + c4 * 4);
            o[c4 * 4 + 0] = fmaxf(acc[c4 * 4 + 0] * inv + b4.x, 0.f);
            o[c4 * 4 + 1] = fmaxf(acc[c4 * 4 + 1] * inv + b4.y, 0.f);
            o[c4 * 4 + 2] = fmaxf(acc[c4 * 4 + 2] * inv + b4.z, 0.f);
            o[c4 * 4 + 3] = fmaxf(acc[c4 * 4 + 3] * inv + b4.w, 0.f);
        }
        if constexpr (OUTBF) {
            __hip_bfloat16 ob[CPL];
            #pragma unroll
            for (int c = 0; c < CPL; ++c) ob[c] = __float2bfloat16(o[c]);
            __hip_bfloat16* op = (__hip_bfloat16*)Outv + (size_t)d * HC + q * CPL;
            #pragma unroll
            for (int c8 = 0; c8 < CPL / 8; ++c8)
                *reinterpret_cast<bf16x8*>(op + c8 * 8) = *reinterpret_cast<bf16x8*>(ob + c8 * 8);
        } else {
            float* op = (float*)Outv + (size_t)d * HC + q * CPL;
            #pragma unroll
            for (int c4 = 0; c4 < CPL / 4; ++c4)
                *reinterpret_cast<float4*>(op + c4 * 4) =
                    make_float4(o[c4*4+0], o[c4*4+1], o[c4*4+2], o[c4*4+3]);
        }
    }
}

// ---------------------------------------------------------------- batch norm (bf16 input)
__global__ __launch_bounds__(256) void bnstats_kernel(const __hip_bfloat16* __restrict__ X,
                                                      float* __restrict__ sums) {
    int c  = threadIdx.x;
    int r0 = blockIdx.x * 200;
    float s = 0.f, q = 0.f;
    for (int r = r0; r < r0 + 200; ++r) {
        float v = bf2f(*(const unsigned short*)(X + (size_t)r * 256 + c));
        s += v; q += v * v;
    }
    atomicAdd(&sums[c], s);
    atomicAdd(&sums[256 + c], q);
}

__global__ __launch_bounds__(256) void bnfinal_kernel(const float* __restrict__ sums,
                                                      const float* __restrict__ gamma,
                                                      const float* __restrict__ beta,
                                                      float* __restrict__ scale,
                                                      float* __restrict__ shift) {
    int c = threadIdx.x;
    float mean = sums[c] / (float)NN;
    float var  = sums[256 + c] / (float)NN - mean * mean;
    float inv  = rsqrtf(var + EPS_BN);
    float sc   = gamma[c] * inv;
    scale[c] = sc;
    shift[c] = beta[c] - mean * sc;
}

// ---------------------------------------------------------------- launch

extern "C" void kernel_launch(void* const* d_in, const int* in_sizes, int n_in,
                              void* d_out, int out_size, void* d_ws, size_t ws_size,
                              hipStream_t stream) {
    const float* x      = (const float*)d_in[0];
    const int*   ei     = (const int*)d_in[1];
    const float* W1     = (const float*)d_in[2];
    const float* a_s1   = (const float*)d_in[3];
    const float* a_d1   = (const float*)d_in[4];
    const float* b1     = (const float*)d_in[5];
    const float* W2     = (const float*)d_in[6];
    const float* a_s2   = (const float*)d_in[7];
    const float* a_d2   = (const float*)d_in[8];
    const float* b2     = (const float*)d_in[9];
    const float* W3     = (const float*)d_in[10];
    const float* a_s3   = (const float*)d_in[11];
    const float* a_d3   = (const float*)d_in[12];
    const float* b3     = (const float*)d_in[13];
    const float* gamma1 = (const float*)d_in[14];
    const float* beta1  = (const float*)d_in[15];
    const float* gamma2 = (const float*)d_in[16];
    const float* beta2  = (const float*)d_in[17];

    char* ws = (char*)d_ws;
    size_t o = 0;
    auto alloc = [&](size_t bytes) -> void* {
        void* p = ws + o;
        o = (o + bytes + 255) & ~size_t(255);
        return p;
    };
    __hip_bfloat16*  Abf  = (__hip_bfloat16*)alloc((size_t)NP * 256 * 2); // attn out (bf16)
    __hip_bfloat16*  Hbf  = (__hip_bfloat16*)alloc((size_t)NP * 256 * 2); // GEMM out
    __hip_bfloat16*  Xbf  = (__hip_bfloat16*)alloc((size_t)NP * 128 * 2); // layer-1 A
    __hip_bfloat16*  WT1  = (__hip_bfloat16*)alloc((size_t)256 * 128 * 2);
    __hip_bfloat16*  WT2  = (__hip_bfloat16*)alloc((size_t)256 * 256 * 2);
    __hip_bfloat16*  WT3  = (__hip_bfloat16*)alloc((size_t)128 * 256 * 2);
    float* bb2   = (float*)alloc(256 * 4);
    float* bb3   = (float*)alloc(128 * 4);
    float* als   = (float*)alloc((size_t)NN * 4 * 4);
    float* ald   = (float*)alloc((size_t)NN * 4 * 4);
    float* sums  = (float*)alloc(512 * 4);
    float* scale = (float*)alloc(256 * 4);
    float* shift = (float*)alloc(256 * 4);
    int*   off   = (int*)alloc((size_t)(NN + 1) * 4);
    int*   cur   = (int*)alloc((size_t)NN * 4);
    int*   cnt   = (int*)alloc((size_t)NN * 4);
    int*   bsum  = (int*)alloc((size_t)NBLK * 4);
    int*   bexc  = (int*)alloc((size_t)NBLK * 4);
    int*   ssrc  = (int*)alloc((size_t)ETOT * 4);
    (void)ws_size; (void)in_sizes; (void)n_in; (void)out_size;

    const int EB = (ETOT + 255) / 256;

    // --- CSR build (shared by all 3 layers)
    hipMemsetAsync(cnt, 0, (size_t)NN * 4, stream);
    count_kernel<<<EB, 256, 0, stream>>>(ei, cnt);
    scanA_kernel<<<NBLK, 256, 0, stream>>>(cnt, off, bsum);
    scanB_kernel<<<1, 256, 0, stream>>>(bsum, bexc, off);
    scanC_kernel<<<NBLK, 256, 0, stream>>>(bexc, off, cur);
    fill_kernel<<<EB, 256, 0, stream>>>(ei, cur, ssrc);

    // --- layer 1
    castw1_kernel<<<128, 256, 0, stream>>>(W1, WT1);
    castx_kernel<<<(int)(((long)NP * 128 / 8 + 255) / 256), 256, 0, stream>>>(x, Xbf);
    mgemm_kernel<128, 256, false><<<dim3(NP / 128, 2), 256, 0, stream>>>(Xbf, WT1, nullptr, Hbf);
    alsd_kernel<256><<<NN / 4, 256, 0, stream>>>(Hbf, a_s1, a_d1, als, ald);
    attn_kernel<256, true><<<NN / 4, 256, 0, stream>>>(Hbf, off, ssrc, als, ald, b1, Abf);

    hipMemsetAsync(sums, 0, 512 * 4, stream);
    bnstats_kernel<<<250, 256, 0, stream>>>(Abf, sums);
    bnfinal_kernel<<<1, 256, 0, stream>>>(sums, gamma1, beta1, scale, shift);
    foldw_kernel<256, 256><<<256, 256, 0, stream>>>(W2, scale, shift, WT2, bb2);

    // --- layer 2 (BN folded into WT2/bb2)
    mgemm_kernel<256, 256, true><<<dim3(NP / 128, 2), 256, 0, stream>>>(Abf, WT2, bb2, Hbf);
    alsd_kernel<256><<<NN / 4, 256, 0, stream>>>(Hbf, a_s2, a_d2, als, ald);
    attn_kernel<256, true><<<NN / 4, 256, 0, stream>>>(Hbf, off, ssrc, als, ald, b2, Abf);

    hipMemsetAsync(sums, 0, 512 * 4, stream);
    bnstats_kernel<<<250, 256, 0, stream>>>(Abf, sums);
    bnfinal_kernel<<<1, 256, 0, stream>>>(sums, gamma2, beta2, scale, shift);
    foldw_kernel<256, 128><<<128, 256, 0, stream>>>(W3, scale, shift, WT3, bb3);

    // --- layer 3 (BN folded into WT3/bb3), f32 output
    mgemm_kernel<256, 128, true><<<dim3(NP / 128, 1), 256, 0, stream>>>(Abf, WT3, bb3, Hbf);
    alsd_kernel<128><<<NN / 4, 256, 0, stream>>>(Hbf, a_s3, a_d3, als, ald);
    attn_kernel<128, false><<<NN / 4, 256, 0, stream>>>(Hbf, off, ssrc, als, ald, b3, d_out);
}

// Round 6
// 384.968 us; speedup vs baseline: 2.8061x; 1.0454x over previous
//
#include <hip/hip_runtime.h>
#include <hip/hip_bf16.h>

// Problem constants (fixed by the reference)
constexpr int NN   = 50000;            // nodes
constexpr int EE   = 800000;           // random edges
constexpr int ETOT = EE + NN;          // + self loops
constexpr int NP   = 50048;            // rows padded to multiple of 128 (391*128)
constexpr int NBLK = (NN + 255) / 256; // 196 scan blocks
constexpr float SLOPE  = 0.2f;
constexpr float EPS_BN = 1e-5f;

typedef __attribute__((ext_vector_type(8))) short bf16x8;
typedef __attribute__((ext_vector_type(4))) float f32x4;

__device__ inline float bf2f(unsigned short u) {
    union { unsigned int i; float f; } c; c.i = ((unsigned int)u) << 16; return c.f;
}

__device__ inline void gload16(const __hip_bfloat16* g, __hip_bfloat16* l) {
    __builtin_amdgcn_global_load_lds(
        (const __attribute__((address_space(1))) unsigned int*)g,
        (__attribute__((address_space(3))) unsigned int*)l, 16, 0, 0);
}

// ---------------------------------------------------------------- CSR build

__global__ __launch_bounds__(256) void count_kernel(const int* __restrict__ ei,
                                                    int* __restrict__ cnt) {
    int j = blockIdx.x * 256 + threadIdx.x;
    if (j >= ETOT) return;
    int dst = (j < EE) ? ei[EE + j] : (j - EE);
    atomicAdd(&cnt[dst], 1);
}

__global__ __launch_bounds__(256) void scanA_kernel(const int* __restrict__ cnt,
                                                    int* __restrict__ off,
                                                    int* __restrict__ bsum) {
    int b = blockIdx.x, t = threadIdx.x;
    int i = b * 256 + t;
    int v = (i < NN) ? cnt[i] : 0;
    int lane = t & 63, w = t >> 6;
    int x = v;
    #pragma unroll
    for (int o = 1; o < 64; o <<= 1) { int y = __shfl_up(x, o); if (lane >= o) x += y; }
    __shared__ int ws[4];
    if (lane == 63) ws[w] = x;
    __syncthreads();
    int wo = 0;
    for (int k = 0; k < w; ++k) wo += ws[k];
    int incl = x + wo;
    if (i < NN) off[i] = incl - v;
    if (t == 255) bsum[b] = incl;
}

__global__ __launch_bounds__(256) void scanB_kernel(const int* __restrict__ bsum,
                                                    int* __restrict__ bexc,
                                                    int* __restrict__ off) {
    int t = threadIdx.x;
    int v = (t < NBLK) ? bsum[t] : 0;
    int lane = t & 63, w = t >> 6;
    int x = v;
    #pragma unroll
    for (int o = 1; o < 64; o <<= 1) { int y = __shfl_up(x, o); if (lane >= o) x += y; }
    __shared__ int ws[4];
    if (lane == 63) ws[w] = x;
    __syncthreads();
    int wo = 0;
    for (int k = 0; k < w; ++k) wo += ws[k];
    int incl = x + wo;
    if (t < NBLK) bexc[t] = incl - v;
    if (t == 255) off[NN] = incl;
}

__global__ __launch_bounds__(256) void scanC_kernel(const int* __restrict__ bexc,
                                                    int* __restrict__ off,
                                                    int* __restrict__ cur) {
    int i = blockIdx.x * 256 + threadIdx.x;
    if (i >= NN) return;
    int v = off[i] + bexc[blockIdx.x];
    off[i] = v;
    cur[i] = v;
}

__global__ __launch_bounds__(256) void fill_kernel(const int* __restrict__ ei,
                                                   int* __restrict__ cursor,
                                                   int* __restrict__ ssrc) {
    int j = blockIdx.x * 256 + threadIdx.x;
    if (j >= ETOT) return;
    int src, dst;
    if (j < EE) { src = ei[j]; dst = ei[EE + j]; }
    else        { src = dst = j - EE; }
    int pos = atomicAdd(&cursor[dst], 1);
    ssrc[pos] = src;
}

// ---------------------------------------------------------------- casts
__global__ __launch_bounds__(256) void castx_kernel(const float* __restrict__ X,
                                                    __hip_bfloat16* __restrict__ Xbf) {
    long e0 = ((long)blockIdx.x * 256 + threadIdx.x) * 8;
    if (e0 >= (long)NP * 128) return;
    int row = (int)(e0 / 128);
    __hip_bfloat16 o[8];
    if (row < NN) {
        float4 v0 = *reinterpret_cast<const float4*>(X + e0);
        float4 v1 = *reinterpret_cast<const float4*>(X + e0 + 4);
        o[0] = __float2bfloat16(v0.x); o[1] = __float2bfloat16(v0.y);
        o[2] = __float2bfloat16(v0.z); o[3] = __float2bfloat16(v0.w);
        o[4] = __float2bfloat16(v1.x); o[5] = __float2bfloat16(v1.y);
        o[6] = __float2bfloat16(v1.z); o[7] = __float2bfloat16(v1.w);
    } else {
        for (int j = 0; j < 8; ++j) o[j] = __float2bfloat16(0.f);
    }
    *reinterpret_cast<bf16x8*>(Xbf + e0) = *reinterpret_cast<bf16x8*>(o);
}

__global__ __launch_bounds__(256) void castw1_kernel(const float* __restrict__ W,
                                                     __hip_bfloat16* __restrict__ WT) {
    int i = blockIdx.x * 256 + threadIdx.x;
    if (i >= 32768) return;
    int c = i / 128, k = i % 128;
    WT[i] = __float2bfloat16(W[(size_t)k * 256 + c]);
}

template <int FIN, int WOUT>
__global__ __launch_bounds__(FIN) void foldw_kernel(const float* __restrict__ W,
                                                    const float* __restrict__ scale,
                                                    const float* __restrict__ shift,
                                                    __hip_bfloat16* __restrict__ WTp,
                                                    float* __restrict__ bb) {
    int c = blockIdx.x, k = threadIdx.x;
    float w = W[(size_t)k * WOUT + c];
    WTp[(size_t)c * FIN + k] = __float2bfloat16(scale[k] * w);
    float p = shift[k] * w;
    #pragma unroll
    for (int o = 1; o < 64; o <<= 1) p += __shfl_xor(p, o);
    __shared__ float ps[FIN / 64];
    if ((k & 63) == 0) ps[k >> 6] = p;
    __syncthreads();
    if (k == 0) {
        float s = 0.f;
        #pragma unroll
        for (int q = 0; q < FIN / 64; ++q) s += ps[q];
        bb[c] = s;
    }
}

// ---------------------------------------------------------------- MFMA GEMM + fused al_src/al_dst
// A:[NP][FIN] bf16, BT:[WOUT][FIN] bf16, Hbf:[NP][WOUT] bf16 (+= bb[c] if FOLD)
// Epilogue also computes als[r,h] = sum_c h[r,h*C+c]*a_src[h,c] (and ald).
template <int FIN, int WOUT, bool FOLD>
__global__ __launch_bounds__(256) void mgemm_kernel(const __hip_bfloat16* __restrict__ A,
                                                    const __hip_bfloat16* __restrict__ BT,
                                                    const float* __restrict__ bb,
                                                    const float* __restrict__ a_src,
                                                    const float* __restrict__ a_dst,
                                                    __hip_bfloat16* __restrict__ Hbf,
                                                    float* __restrict__ als,
                                                    float* __restrict__ ald) {
    __shared__ __hip_bfloat16 As[128 * 32];
    __shared__ __hip_bfloat16 Bs[128 * 32];
    int t = threadIdx.x;
    int lane = t & 63, w = t >> 6;
    int row0 = blockIdx.x * 128;
    int col0 = blockIdx.y * 128;
    int wr = w >> 1, wc = w & 1;

    f32x4 acc[4][4];
    #pragma unroll
    for (int m = 0; m < 4; ++m)
        #pragma unroll
        for (int n = 0; n < 4; ++n) acc[m][n] = (f32x4){0.f, 0.f, 0.f, 0.f};

    int srow = w * 32 + (lane >> 2);
    int sbc  = (lane & 3) * 8;
    const __hip_bfloat16* gA0 = A  + (size_t)(row0 + srow)      * FIN + sbc;
    const __hip_bfloat16* gA1 = A  + (size_t)(row0 + srow + 16) * FIN + sbc;
    const __hip_bfloat16* gB0 = BT + (size_t)(col0 + srow)      * FIN + sbc;
    const __hip_bfloat16* gB1 = BT + (size_t)(col0 + srow + 16) * FIN + sbc;
    __hip_bfloat16* lA0 = As + w * 1024;
    __hip_bfloat16* lA1 = As + w * 1024 + 512;
    __hip_bfloat16* lB0 = Bs + w * 1024;
    __hip_bfloat16* lB1 = Bs + w * 1024 + 512;

    int rA = (wr * 64 + (lane & 15)) * 32 + (lane >> 4) * 8;
    int rB = (wc * 64 + (lane & 15)) * 32 + (lane >> 4) * 8;

    for (int k0 = 0; k0 < FIN; k0 += 32) {
        gload16(gA0 + k0, lA0);
        gload16(gA1 + k0, lA1);
        gload16(gB0 + k0, lB0);
        gload16(gB1 + k0, lB1);
        __syncthreads();
        bf16x8 af[4], bfr[4];
        #pragma unroll
        for (int m = 0; m < 4; ++m) af[m]  = *reinterpret_cast<const bf16x8*>(As + rA + m * 16 * 32);
        #pragma unroll
        for (int n = 0; n < 4; ++n) bfr[n] = *reinterpret_cast<const bf16x8*>(Bs + rB + n * 16 * 32);
        #pragma unroll
        for (int m = 0; m < 4; ++m)
            #pragma unroll
            for (int n = 0; n < 4; ++n)
                acc[m][n] = __builtin_amdgcn_mfma_f32_16x16x32_bf16(af[m], bfr[n], acc[m][n], 0, 0, 0);
        __syncthreads();
    }

    int cih = lane & 15;

    // fold BN bias into acc (so Hbf AND als see it)
    if constexpr (FOLD) {
        #pragma unroll
        for (int n = 0; n < 4; ++n) {
            float badd = bb[col0 + wc * 64 + n * 16 + cih];
            #pragma unroll
            for (int m = 0; m < 4; ++m)
                #pragma unroll
                for (int j = 0; j < 4; ++j) acc[m][n][j] += badd;
        }
    }

    // attention-logit vectors for this wave's 64-col span
    float asv[4], adv[4];
    int headw = 0;
    if constexpr (WOUT == 256) {
        headw = (col0 >> 6) + wc;          // one head per wave (C=64)
        #pragma unroll
        for (int n = 0; n < 4; ++n) {
            asv[n] = a_src[headw * 64 + n * 16 + cih];
            adv[n] = a_dst[headw * 64 + n * 16 + cih];
        }
    } else {                               // WOUT==128: two heads per wave (C=32)
        #pragma unroll
        for (int n = 0; n < 4; ++n) {
            int hh = wc * 2 + (n >> 1);
            asv[n] = a_src[hh * 32 + (n & 1) * 16 + cih];
            adv[n] = a_dst[hh * 32 + (n & 1) * 16 + cih];
        }
    }

    // per-row reduction over the 64 cols held by this 16-lane row-group
    #pragma unroll
    for (int m = 0; m < 4; ++m) {
        #pragma unroll
        for (int j = 0; j < 4; ++j) {
            int r = row0 + wr * 64 + m * 16 + (lane >> 4) * 4 + j;
            if constexpr (WOUT == 256) {
                float vs = acc[m][0][j] * asv[0] + acc[m][1][j] * asv[1]
                         + acc[m][2][j] * asv[2] + acc[m][3][j] * asv[3];
                float vd = acc[m][0][j] * adv[0] + acc[m][1][j] * adv[1]
                         + acc[m][2][j] * adv[2] + acc[m][3][j] * adv[3];
                #pragma unroll
                for (int o = 1; o < 16; o <<= 1) {
                    vs += __shfl_xor(vs, o);
                    vd += __shfl_xor(vd, o);
                }
                if (cih == 0) {
                    als[(size_t)r * 4 + headw] = vs;
                    ald[(size_t)r * 4 + headw] = vd;
                }
            } else {
                float vs0 = acc[m][0][j] * asv[0] + acc[m][1][j] * asv[1];
                float vs1 = acc[m][2][j] * asv[2] + acc[m][3][j] * asv[3];
                float vd0 = acc[m][0][j] * adv[0] + acc[m][1][j] * adv[1];
                float vd1 = acc[m][2][j] * adv[2] + acc[m][3][j] * adv[3];
                #pragma unroll
                for (int o = 1; o < 16; o <<= 1) {
                    vs0 += __shfl_xor(vs0, o); vs1 += __shfl_xor(vs1, o);
                    vd0 += __shfl_xor(vd0, o); vd1 += __shfl_xor(vd1, o);
                }
                if (cih == 0) {
                    als[(size_t)r * 4 + wc * 2]     = vs0;
                    als[(size_t)r * 4 + wc * 2 + 1] = vs1;
                    ald[(size_t)r * 4 + wc * 2]     = vd0;
                    ald[(size_t)r * 4 + wc * 2 + 1] = vd1;
                }
            }
        }
    }

    // store H
    #pragma unroll
    for (int n = 0; n < 4; ++n) {
        int c = col0 + wc * 64 + n * 16 + cih;
        #pragma unroll
        for (int m = 0; m < 4; ++m) {
            int r = row0 + wr * 64 + m * 16 + (lane >> 4) * 4;
            #pragma unroll
            for (int j = 0; j < 4; ++j)
                Hbf[(size_t)(r + j) * WOUT + c] = __float2bfloat16(acc[m][n][j]);
        }
    }
}

// ---------------------------------------------------------------- fused one-pass edge softmax + aggregate
// One 16-lane group per destination (4 dsts/wave, 16 dsts/block), 4-edge unroll.
// Lane q of a group accumulates cols [q*CPL, (q+1)*CPL); den is lane-local (per head).
template <int HC, bool OUTBF>
__global__ __launch_bounds__(256) void attn_kernel(const __hip_bfloat16* __restrict__ Hm,
                                                   const int* __restrict__ off,
                                                   const int* __restrict__ ssrc,
                                                   const float* __restrict__ als,
                                                   const float* __restrict__ ald,
                                                   const float* __restrict__ bias,
                                                   void* __restrict__ Outv) {
    constexpr int CPL = HC / 16;           // 16 (HC=256) or 8 (HC=128)
    int wid  = threadIdx.x >> 6;
    int lane = threadIdx.x & 63;
    int g    = lane >> 4;
    int q    = lane & 15;
    int d    = blockIdx.x * 16 + wid * 4 + g;
    int head = q >> 2;

    int e0 = off[d], e1 = off[d + 1];
    float aldh = ald[(size_t)d * 4 + head];

    float acc[CPL];
    #pragma unroll
    for (int c = 0; c < CPL; ++c) acc[c] = 0.f;
    float den = 0.f;

    int j = e0;
    for (; j + 3 < e1; j += 4) {
        int s0 = ssrc[j], s1 = ssrc[j + 1], s2 = ssrc[j + 2], s3 = ssrc[j + 3];
        float x0 = als[(size_t)s0 * 4 + head] + aldh;
        float x1 = als[(size_t)s1 * 4 + head] + aldh;
        float x2 = als[(size_t)s2 * 4 + head] + aldh;
        float x3 = als[(size_t)s3 * 4 + head] + aldh;
        x0 = (x0 > 0.f) ? x0 : SLOPE * x0;
        x1 = (x1 > 0.f) ? x1 : SLOPE * x1;
        x2 = (x2 > 0.f) ? x2 : SLOPE * x2;
        x3 = (x3 > 0.f) ? x3 : SLOPE * x3;
        float w0 = __expf(x0), w1 = __expf(x1), w2 = __expf(x2), w3 = __expf(x3);
        den += (w0 + w1) + (w2 + w3);
        const __hip_bfloat16* p0 = Hm + (size_t)s0 * HC + q * CPL;
        const __hip_bfloat16* p1 = Hm + (size_t)s1 * HC + q * CPL;
        const __hip_bfloat16* p2 = Hm + (size_t)s2 * HC + q * CPL;
        const __hip_bfloat16* p3 = Hm + (size_t)s3 * HC + q * CPL;
        if constexpr (CPL == 16) {
            bf16x8 a0 = *reinterpret_cast<const bf16x8*>(p0);
            bf16x8 a1 = *reinterpret_cast<const bf16x8*>(p0 + 8);
            bf16x8 b0 = *reinterpret_cast<const bf16x8*>(p1);
            bf16x8 b1 = *reinterpret_cast<const bf16x8*>(p1 + 8);
            bf16x8 c0 = *reinterpret_cast<const bf16x8*>(p2);
            bf16x8 c1 = *reinterpret_cast<const bf16x8*>(p2 + 8);
            bf16x8 d0 = *reinterpret_cast<const bf16x8*>(p3);
            bf16x8 d1 = *reinterpret_cast<const bf16x8*>(p3 + 8);
            #pragma unroll
            for (int c = 0; c < 8; ++c) {
                acc[c]     += w0 * bf2f((unsigned short)a0[c]) + w1 * bf2f((unsigned short)b0[c])
                            + w2 * bf2f((unsigned short)c0[c]) + w3 * bf2f((unsigned short)d0[c]);
                acc[8 + c] += w0 * bf2f((unsigned short)a1[c]) + w1 * bf2f((unsigned short)b1[c])
                            + w2 * bf2f((unsigned short)c1[c]) + w3 * bf2f((unsigned short)d1[c]);
            }
        } else {
            bf16x8 a0 = *reinterpret_cast<const bf16x8*>(p0);
            bf16x8 b0 = *reinterpret_cast<const bf16x8*>(p1);
            bf16x8 c0 = *reinterpret_cast<const bf16x8*>(p2);
            bf16x8 d0 = *reinterpret_cast<const bf16x8*>(p3);
            #pragma unroll
            for (int c = 0; c < 8; ++c)
                acc[c] += w0 * bf2f((unsigned short)a0[c]) + w1 * bf2f((unsigned short)b0[c])
                        + w2 * bf2f((unsigned short)c0[c]) + w3 * bf2f((unsigned short)d0[c]);
        }
    }
    for (; j < e1; ++j) {
        int s0 = ssrc[j];
        float x0 = als[(size_t)s0 * 4 + head] + aldh;
        x0 = (x0 > 0.f) ? x0 : SLOPE * x0;
        float w0 = __expf(x0);
        den += w0;
        const __hip_bfloat16* p0 = Hm + (size_t)s0 * HC + q * CPL;
        if constexpr (CPL == 16) {
            bf16x8 a0 = *reinterpret_cast<const bf16x8*>(p0);
            bf16x8 a1 = *reinterpret_cast<const bf16x8*>(p0 + 8);
            #pragma unroll
            for (int c = 0; c < 8; ++c) {
                acc[c]     += w0 * bf2f((unsigned short)a0[c]);
                acc[8 + c] += w0 * bf2f((unsigned short)a1[c]);
            }
        } else {
            bf16x8 a0 = *reinterpret_cast<const bf16x8*>(p0);
            #pragma unroll
            for (int c = 0; c < 8; ++c) acc[c] += w0 * bf2f((unsigned short)a0[c]);
        }
    }

    float inv = 1.f / (den + 1e-16f);

    float o[CPL];
    #pragma unroll
    for (int c4 = 0; c4 < CPL / 4; ++c4) {
        float4 b4 = *reinterpret_cast<const float4*>(bias + q * CPL + c4 * 4);
        o[c4 * 4 + 0] = fmaxf(acc[c4 * 4 + 0] * inv + b4.x, 0.f);
        o[c4 * 4 + 1] = fmaxf(acc[c4 * 4 + 1] * inv + b4.y, 0.f);
        o[c4 * 4 + 2] = fmaxf(acc[c4 * 4 + 2] * inv + b4.z, 0.f);
        o[c4 * 4 + 3] = fmaxf(acc[c4 * 4 + 3] * inv + b4.w, 0.f);
    }
    if constexpr (OUTBF) {
        __hip_bfloat16 ob[CPL];
        #pragma unroll
        for (int c = 0; c < CPL; ++c) ob[c] = __float2bfloat16(o[c]);
        __hip_bfloat16* op = (__hip_bfloat16*)Outv + (size_t)d * HC + q * CPL;
        #pragma unroll
        for (int c8 = 0; c8 < CPL / 8; ++c8)
            *reinterpret_cast<bf16x8*>(op + c8 * 8) = *reinterpret_cast<bf16x8*>(ob + c8 * 8);
    } else {
        float* op = (float*)Outv + (size_t)d * HC + q * CPL;
        #pragma unroll
        for (int c4 = 0; c4 < CPL / 4; ++c4)
            *reinterpret_cast<float4*>(op + c4 * 4) =
                make_float4(o[c4*4+0], o[c4*4+1], o[c4*4+2], o[c4*4+3]);
    }
}

// ---------------------------------------------------------------- batch norm (bf16 input)
__global__ __launch_bounds__(256) void bnstats_kernel(const __hip_bfloat16* __restrict__ X,
                                                      float* __restrict__ sums) {
    int c  = threadIdx.x;
    int r0 = blockIdx.x * 200;
    float s = 0.f, q = 0.f;
    for (int r = r0; r < r0 + 200; ++r) {
        float v = bf2f(*(const unsigned short*)(X + (size_t)r * 256 + c));
        s += v; q += v * v;
    }
    atomicAdd(&sums[c], s);
    atomicAdd(&sums[256 + c], q);
}

__global__ __launch_bounds__(256) void bnfinal_kernel(const float* __restrict__ sums,
                                                      const float* __restrict__ gamma,
                                                      const float* __restrict__ beta,
                                                      float* __restrict__ scale,
                                                      float* __restrict__ shift) {
    int c = threadIdx.x;
    float mean = sums[c] / (float)NN;
    float var  = sums[256 + c] / (float)NN - mean * mean;
    float inv  = rsqrtf(var + EPS_BN);
    float sc   = gamma[c] * inv;
    scale[c] = sc;
    shift[c] = beta[c] - mean * sc;
}

// ---------------------------------------------------------------- launch

extern "C" void kernel_launch(void* const* d_in, const int* in_sizes, int n_in,
                              void* d_out, int out_size, void* d_ws, size_t ws_size,
                              hipStream_t stream) {
    const float* x      = (const float*)d_in[0];
    const int*   ei     = (const int*)d_in[1];
    const float* W1     = (const float*)d_in[2];
    const float* a_s1   = (const float*)d_in[3];
    const float* a_d1   = (const float*)d_in[4];
    const float* b1     = (const float*)d_in[5];
    const float* W2     = (const float*)d_in[6];
    const float* a_s2   = (const float*)d_in[7];
    const float* a_d2   = (const float*)d_in[8];
    const float* b2     = (const float*)d_in[9];
    const float* W3     = (const float*)d_in[10];
    const float* a_s3   = (const float*)d_in[11];
    const float* a_d3   = (const float*)d_in[12];
    const float* b3     = (const float*)d_in[13];
    const float* gamma1 = (const float*)d_in[14];
    const float* beta1  = (const float*)d_in[15];
    const float* gamma2 = (const float*)d_in[16];
    const float* beta2  = (const float*)d_in[17];

    char* ws = (char*)d_ws;
    size_t o = 0;
    auto alloc = [&](size_t bytes) -> void* {
        void* p = ws + o;
        o = (o + bytes + 255) & ~size_t(255);
        return p;
    };
    __hip_bfloat16*  Abf  = (__hip_bfloat16*)alloc((size_t)NP * 256 * 2); // attn out (bf16)
    __hip_bfloat16*  Hbf  = (__hip_bfloat16*)alloc((size_t)NP * 256 * 2); // GEMM out
    __hip_bfloat16*  Xbf  = (__hip_bfloat16*)alloc((size_t)NP * 128 * 2); // layer-1 A
    __hip_bfloat16*  WT1  = (__hip_bfloat16*)alloc((size_t)256 * 128 * 2);
    __hip_bfloat16*  WT2  = (__hip_bfloat16*)alloc((size_t)256 * 256 * 2);
    __hip_bfloat16*  WT3  = (__hip_bfloat16*)alloc((size_t)128 * 256 * 2);
    float* bb2   = (float*)alloc(256 * 4);
    float* bb3   = (float*)alloc(128 * 4);
    float* als   = (float*)alloc((size_t)NP * 4 * 4);
    float* ald   = (float*)alloc((size_t)NP * 4 * 4);
    float* sums  = (float*)alloc(512 * 4);
    float* scale = (float*)alloc(256 * 4);
    float* shift = (float*)alloc(256 * 4);
    int*   off   = (int*)alloc((size_t)(NN + 1) * 4);
    int*   cur   = (int*)alloc((size_t)NN * 4);
    int*   cnt   = (int*)alloc((size_t)NN * 4);
    int*   bsum  = (int*)alloc((size_t)NBLK * 4);
    int*   bexc  = (int*)alloc((size_t)NBLK * 4);
    int*   ssrc  = (int*)alloc((size_t)ETOT * 4);
    (void)ws_size; (void)in_sizes; (void)n_in; (void)out_size;

    const int EB = (ETOT + 255) / 256;

    // --- CSR build (shared by all 3 layers)
    hipMemsetAsync(cnt, 0, (size_t)NN * 4, stream);
    count_kernel<<<EB, 256, 0, stream>>>(ei, cnt);
    scanA_kernel<<<NBLK, 256, 0, stream>>>(cnt, off, bsum);
    scanB_kernel<<<1, 256, 0, stream>>>(bsum, bexc, off);
    scanC_kernel<<<NBLK, 256, 0, stream>>>(bexc, off, cur);
    fill_kernel<<<EB, 256, 0, stream>>>(ei, cur, ssrc);

    // --- layer 1
    castw1_kernel<<<128, 256, 0, stream>>>(W1, WT1);
    castx_kernel<<<(int)(((long)NP * 128 / 8 + 255) / 256), 256, 0, stream>>>(x, Xbf);
    mgemm_kernel<128, 256, false><<<dim3(NP / 128, 2), 256, 0, stream>>>(
        Xbf, WT1, nullptr, a_s1, a_d1, Hbf, als, ald);
    attn_kernel<256, true><<<NN / 16, 256, 0, stream>>>(Hbf, off, ssrc, als, ald, b1, Abf);

    hipMemsetAsync(sums, 0, 512 * 4, stream);
    bnstats_kernel<<<250, 256, 0, stream>>>(Abf, sums);
    bnfinal_kernel<<<1, 256, 0, stream>>>(sums, gamma1, beta1, scale, shift);
    foldw_kernel<256, 256><<<256, 256, 0, stream>>>(W2, scale, shift, WT2, bb2);

    // --- layer 2 (BN folded into WT2/bb2)
    mgemm_kernel<256, 256, true><<<dim3(NP / 128, 2), 256, 0, stream>>>(
        Abf, WT2, bb2, a_s2, a_d2, Hbf, als, ald);
    attn_kernel<256, true><<<NN / 16, 256, 0, stream>>>(Hbf, off, ssrc, als, ald, b2, Abf);

    hipMemsetAsync(sums, 0, 512 * 4, stream);
    bnstats_kernel<<<250, 256, 0, stream>>>(Abf, sums);
    bnfinal_kernel<<<1, 256, 0, stream>>>(sums, gamma2, beta2, scale, shift);
    foldw_kernel<256, 128><<<128, 256, 0, stream>>>(W3, scale, shift, WT3, bb3);

    // --- layer 3 (BN folded into WT3/bb3), f32 output
    mgemm_kernel<256, 128, true><<<dim3(NP / 128, 1), 256, 0, stream>>>(
        Abf, WT3, bb3, a_s3, a_d3, Hbf, als, ald);
    attn_kernel<128, false><<<NN / 16, 256, 0, stream>>>(Hbf, off, ssrc, als, ald, b3, d_out);
}

// Round 7
// 382.121 us; speedup vs baseline: 2.8270x; 1.0074x over previous
//
#include <hip/hip_runtime.h>
#include <hip/hip_bf16.h>

// Problem constants (fixed by the reference)
constexpr int NN   = 50000;            // nodes
constexpr int EE   = 800000;           // random edges
constexpr int ETOT = EE + NN;          // + self loops
constexpr int NP   = 50048;            // rows padded to multiple of 128 (391*128)
constexpr int NBLK = (NN + 255) / 256; // 196 scan blocks
constexpr float SLOPE  = 0.2f;
constexpr float EPS_BN = 1e-5f;

typedef __attribute__((ext_vector_type(8))) short bf16x8;
typedef __attribute__((ext_vector_type(4))) float f32x4;

__device__ inline float bf2f(unsigned short u) {
    union { unsigned int i; float f; } c; c.i = ((unsigned int)u) << 16; return c.f;
}

__device__ inline void gload16(const __hip_bfloat16* g, __hip_bfloat16* l) {
    __builtin_amdgcn_global_load_lds(
        (const __attribute__((address_space(1))) unsigned int*)g,
        (__attribute__((address_space(3))) unsigned int*)l, 16, 0, 0);
}

// ---------------------------------------------------------------- CSR build

__global__ __launch_bounds__(256) void count_kernel(const int* __restrict__ ei,
                                                    int* __restrict__ cnt) {
    int j = blockIdx.x * 256 + threadIdx.x;
    if (j >= ETOT) return;
    int dst = (j < EE) ? ei[EE + j] : (j - EE);
    atomicAdd(&cnt[dst], 1);
}

__global__ __launch_bounds__(256) void scanA_kernel(const int* __restrict__ cnt,
                                                    int* __restrict__ off,
                                                    int* __restrict__ bsum) {
    int b = blockIdx.x, t = threadIdx.x;
    int i = b * 256 + t;
    int v = (i < NN) ? cnt[i] : 0;
    int lane = t & 63, w = t >> 6;
    int x = v;
    #pragma unroll
    for (int o = 1; o < 64; o <<= 1) { int y = __shfl_up(x, o); if (lane >= o) x += y; }
    __shared__ int ws[4];
    if (lane == 63) ws[w] = x;
    __syncthreads();
    int wo = 0;
    for (int k = 0; k < w; ++k) wo += ws[k];
    int incl = x + wo;
    if (i < NN) off[i] = incl - v;
    if (t == 255) bsum[b] = incl;
}

__global__ __launch_bounds__(256) void scanB_kernel(const int* __restrict__ bsum,
                                                    int* __restrict__ bexc,
                                                    int* __restrict__ off) {
    int t = threadIdx.x;
    int v = (t < NBLK) ? bsum[t] : 0;
    int lane = t & 63, w = t >> 6;
    int x = v;
    #pragma unroll
    for (int o = 1; o < 64; o <<= 1) { int y = __shfl_up(x, o); if (lane >= o) x += y; }
    __shared__ int ws[4];
    if (lane == 63) ws[w] = x;
    __syncthreads();
    int wo = 0;
    for (int k = 0; k < w; ++k) wo += ws[k];
    int incl = x + wo;
    if (t < NBLK) bexc[t] = incl - v;
    if (t == 255) off[NN] = incl;
}

__global__ __launch_bounds__(256) void scanC_kernel(const int* __restrict__ bexc,
                                                    int* __restrict__ off,
                                                    int* __restrict__ cur) {
    int i = blockIdx.x * 256 + threadIdx.x;
    if (i >= NN) return;
    int v = off[i] + bexc[blockIdx.x];
    off[i] = v;
    cur[i] = v;
}

__global__ __launch_bounds__(256) void fill_kernel(const int* __restrict__ ei,
                                                   int* __restrict__ cursor,
                                                   int* __restrict__ ssrc) {
    int j = blockIdx.x * 256 + threadIdx.x;
    if (j >= ETOT) return;
    int src, dst;
    if (j < EE) { src = ei[j]; dst = ei[EE + j]; }
    else        { src = dst = j - EE; }
    int pos = atomicAdd(&cursor[dst], 1);
    ssrc[pos] = src;
}

// ---------------------------------------------------------------- layer-1 casts (fused)
// blocks [0, XB): x f32 [NN][128] -> Xbf [NP][128]; blocks [XB, XB+128): W1 transpose
constexpr int XB = (int)(((long)NP * 128 / 8 + 255) / 256);
__global__ __launch_bounds__(256) void castwx_kernel(const float* __restrict__ X,
                                                     const float* __restrict__ W,
                                                     __hip_bfloat16* __restrict__ Xbf,
                                                     __hip_bfloat16* __restrict__ WT) {
    int b = blockIdx.x;
    if (b < XB) {
        long e0 = ((long)b * 256 + threadIdx.x) * 8;
        if (e0 >= (long)NP * 128) return;
        int row = (int)(e0 / 128);
        __hip_bfloat16 o[8];
        if (row < NN) {
            float4 v0 = *reinterpret_cast<const float4*>(X + e0);
            float4 v1 = *reinterpret_cast<const float4*>(X + e0 + 4);
            o[0] = __float2bfloat16(v0.x); o[1] = __float2bfloat16(v0.y);
            o[2] = __float2bfloat16(v0.z); o[3] = __float2bfloat16(v0.w);
            o[4] = __float2bfloat16(v1.x); o[5] = __float2bfloat16(v1.y);
            o[6] = __float2bfloat16(v1.z); o[7] = __float2bfloat16(v1.w);
        } else {
            for (int j = 0; j < 8; ++j) o[j] = __float2bfloat16(0.f);
        }
        *reinterpret_cast<bf16x8*>(Xbf + e0) = *reinterpret_cast<bf16x8*>(o);
    } else {
        int i = (b - XB) * 256 + threadIdx.x;
        int c = i / 128, k = i % 128;
        WT[i] = __float2bfloat16(W[(size_t)k * 256 + c]);
    }
}

// fold BN (from raw sums) + transpose next-layer W; bb[c] = sum_k shift[k]*W[k][c]
template <int WOUT>
__global__ __launch_bounds__(256) void foldw_kernel(const float* __restrict__ W,
                                                    const float* __restrict__ sums,
                                                    const float* __restrict__ gamma,
                                                    const float* __restrict__ beta,
                                                    __hip_bfloat16* __restrict__ WTp,
                                                    float* __restrict__ bb) {
    int c = blockIdx.x, k = threadIdx.x;
    float mean = sums[k] / (float)NN;
    float var  = sums[256 + k] / (float)NN - mean * mean;
    float inv  = rsqrtf(var + EPS_BN);
    float sc   = gamma[k] * inv;
    float sh   = beta[k] - mean * sc;
    float w = W[(size_t)k * WOUT + c];
    WTp[(size_t)c * 256 + k] = __float2bfloat16(sc * w);
    float p = sh * w;
    #pragma unroll
    for (int o = 1; o < 64; o <<= 1) p += __shfl_xor(p, o);
    __shared__ float ps[4];
    if ((k & 63) == 0) ps[k >> 6] = p;
    __syncthreads();
    if (k == 0) bb[c] = ps[0] + ps[1] + ps[2] + ps[3];
}

// ---------------------------------------------------------------- MFMA GEMM + fused al_src/al_dst
template <int FIN, int WOUT, bool FOLD>
__global__ __launch_bounds__(256) void mgemm_kernel(const __hip_bfloat16* __restrict__ A,
                                                    const __hip_bfloat16* __restrict__ BT,
                                                    const float* __restrict__ bb,
                                                    const float* __restrict__ a_src,
                                                    const float* __restrict__ a_dst,
                                                    __hip_bfloat16* __restrict__ Hbf,
                                                    float* __restrict__ als,
                                                    float* __restrict__ ald) {
    __shared__ __hip_bfloat16 As[128 * 32];
    __shared__ __hip_bfloat16 Bs[128 * 32];
    int t = threadIdx.x;
    int lane = t & 63, w = t >> 6;
    int row0 = blockIdx.x * 128;
    int col0 = blockIdx.y * 128;
    int wr = w >> 1, wc = w & 1;

    f32x4 acc[4][4];
    #pragma unroll
    for (int m = 0; m < 4; ++m)
        #pragma unroll
        for (int n = 0; n < 4; ++n) acc[m][n] = (f32x4){0.f, 0.f, 0.f, 0.f};

    int srow = w * 32 + (lane >> 2);
    int sbc  = (lane & 3) * 8;
    const __hip_bfloat16* gA0 = A  + (size_t)(row0 + srow)      * FIN + sbc;
    const __hip_bfloat16* gA1 = A  + (size_t)(row0 + srow + 16) * FIN + sbc;
    const __hip_bfloat16* gB0 = BT + (size_t)(col0 + srow)      * FIN + sbc;
    const __hip_bfloat16* gB1 = BT + (size_t)(col0 + srow + 16) * FIN + sbc;
    __hip_bfloat16* lA0 = As + w * 1024;
    __hip_bfloat16* lA1 = As + w * 1024 + 512;
    __hip_bfloat16* lB0 = Bs + w * 1024;
    __hip_bfloat16* lB1 = Bs + w * 1024 + 512;

    int rA = (wr * 64 + (lane & 15)) * 32 + (lane >> 4) * 8;
    int rB = (wc * 64 + (lane & 15)) * 32 + (lane >> 4) * 8;

    for (int k0 = 0; k0 < FIN; k0 += 32) {
        gload16(gA0 + k0, lA0);
        gload16(gA1 + k0, lA1);
        gload16(gB0 + k0, lB0);
        gload16(gB1 + k0, lB1);
        __syncthreads();
        bf16x8 af[4], bfr[4];
        #pragma unroll
        for (int m = 0; m < 4; ++m) af[m]  = *reinterpret_cast<const bf16x8*>(As + rA + m * 16 * 32);
        #pragma unroll
        for (int n = 0; n < 4; ++n) bfr[n] = *reinterpret_cast<const bf16x8*>(Bs + rB + n * 16 * 32);
        #pragma unroll
        for (int m = 0; m < 4; ++m)
            #pragma unroll
            for (int n = 0; n < 4; ++n)
                acc[m][n] = __builtin_amdgcn_mfma_f32_16x16x32_bf16(af[m], bfr[n], acc[m][n], 0, 0, 0);
        __syncthreads();
    }

    int cih = lane & 15;

    if constexpr (FOLD) {
        #pragma unroll
        for (int n = 0; n < 4; ++n) {
            float badd = bb[col0 + wc * 64 + n * 16 + cih];
            #pragma unroll
            for (int m = 0; m < 4; ++m)
                #pragma unroll
                for (int j = 0; j < 4; ++j) acc[m][n][j] += badd;
        }
    }

    float asv[4], adv[4];
    int headw = 0;
    if constexpr (WOUT == 256) {
        headw = (col0 >> 6) + wc;
        #pragma unroll
        for (int n = 0; n < 4; ++n) {
            asv[n] = a_src[headw * 64 + n * 16 + cih];
            adv[n] = a_dst[headw * 64 + n * 16 + cih];
        }
    } else {
        #pragma unroll
        for (int n = 0; n < 4; ++n) {
            int hh = wc * 2 + (n >> 1);
            asv[n] = a_src[hh * 32 + (n & 1) * 16 + cih];
            adv[n] = a_dst[hh * 32 + (n & 1) * 16 + cih];
        }
    }

    #pragma unroll
    for (int m = 0; m < 4; ++m) {
        #pragma unroll
        for (int j = 0; j < 4; ++j) {
            int r = row0 + wr * 64 + m * 16 + (lane >> 4) * 4 + j;
            if constexpr (WOUT == 256) {
                float vs = acc[m][0][j] * asv[0] + acc[m][1][j] * asv[1]
                         + acc[m][2][j] * asv[2] + acc[m][3][j] * asv[3];
                float vd = acc[m][0][j] * adv[0] + acc[m][1][j] * adv[1]
                         + acc[m][2][j] * adv[2] + acc[m][3][j] * adv[3];
                #pragma unroll
                for (int o = 1; o < 16; o <<= 1) {
                    vs += __shfl_xor(vs, o);
                    vd += __shfl_xor(vd, o);
                }
                if (cih == 0) {
                    als[(size_t)r * 4 + headw] = vs;
                    ald[(size_t)r * 4 + headw] = vd;
                }
            } else {
                float vs0 = acc[m][0][j] * asv[0] + acc[m][1][j] * asv[1];
                float vs1 = acc[m][2][j] * asv[2] + acc[m][3][j] * asv[3];
                float vd0 = acc[m][0][j] * adv[0] + acc[m][1][j] * adv[1];
                float vd1 = acc[m][2][j] * adv[2] + acc[m][3][j] * adv[3];
                #pragma unroll
                for (int o = 1; o < 16; o <<= 1) {
                    vs0 += __shfl_xor(vs0, o); vs1 += __shfl_xor(vs1, o);
                    vd0 += __shfl_xor(vd0, o); vd1 += __shfl_xor(vd1, o);
                }
                if (cih == 0) {
                    als[(size_t)r * 4 + wc * 2]     = vs0;
                    als[(size_t)r * 4 + wc * 2 + 1] = vs1;
                    ald[(size_t)r * 4 + wc * 2]     = vd0;
                    ald[(size_t)r * 4 + wc * 2 + 1] = vd1;
                }
            }
        }
    }

    #pragma unroll
    for (int n = 0; n < 4; ++n) {
        int c = col0 + wc * 64 + n * 16 + cih;
        #pragma unroll
        for (int m = 0; m < 4; ++m) {
            int r = row0 + wr * 64 + m * 16 + (lane >> 4) * 4;
            #pragma unroll
            for (int j = 0; j < 4; ++j)
                Hbf[(size_t)(r + j) * WOUT + c] = __float2bfloat16(acc[m][n][j]);
        }
    }
}

// ---------------------------------------------------------------- fused one-pass edge softmax + aggregate
// HC=256: PACKED dual-chunk layout. Lane q owns cols [8q,8q+8) (head q>>3) and
// [128+8q, 128+8q+8) (head 2+(q>>3)). Every 16B load instruction is fully packed
// (16 lanes x 16B consecutive per row) -> minimal cacheline touches in L1/TA.
__global__ __launch_bounds__(256) void attn256_kernel(const __hip_bfloat16* __restrict__ Hm,
                                                      const int* __restrict__ off,
                                                      const int* __restrict__ ssrc,
                                                      const float* __restrict__ als,
                                                      const float* __restrict__ ald,
                                                      const float* __restrict__ bias,
                                                      __hip_bfloat16* __restrict__ Out) {
    int wid  = threadIdx.x >> 6;
    int lane = threadIdx.x & 63;
    int g    = lane >> 4;
    int q    = lane & 15;
    int d    = blockIdx.x * 16 + wid * 4 + g;
    int hA   = q >> 3;             // head of chunk A (cols 8q..)
    // chunk B head = hA + 2       (cols 128+8q..)

    int e0 = off[d], e1 = off[d + 1];
    float aldA = ald[(size_t)d * 4 + hA];
    float aldB = ald[(size_t)d * 4 + hA + 2];

    float accA[8], accB[8];
    #pragma unroll
    for (int c = 0; c < 8; ++c) { accA[c] = 0.f; accB[c] = 0.f; }
    float denA = 0.f, denB = 0.f;

    int j = e0;
    for (; j + 3 < e1; j += 4) {
        int s0 = ssrc[j], s1 = ssrc[j + 1], s2 = ssrc[j + 2], s3 = ssrc[j + 3];
        const __hip_bfloat16* r0 = Hm + (size_t)s0 * 256 + q * 8;
        const __hip_bfloat16* r1 = Hm + (size_t)s1 * 256 + q * 8;
        const __hip_bfloat16* r2 = Hm + (size_t)s2 * 256 + q * 8;
        const __hip_bfloat16* r3 = Hm + (size_t)s3 * 256 + q * 8;
        bf16x8 a0 = *reinterpret_cast<const bf16x8*>(r0);
        bf16x8 b0 = *reinterpret_cast<const bf16x8*>(r0 + 128);
        bf16x8 a1 = *reinterpret_cast<const bf16x8*>(r1);
        bf16x8 b1 = *reinterpret_cast<const bf16x8*>(r1 + 128);
        bf16x8 a2 = *reinterpret_cast<const bf16x8*>(r2);
        bf16x8 b2 = *reinterpret_cast<const bf16x8*>(r2 + 128);
        bf16x8 a3 = *reinterpret_cast<const bf16x8*>(r3);
        bf16x8 b3 = *reinterpret_cast<const bf16x8*>(r3 + 128);
        float xA0 = als[(size_t)s0 * 4 + hA] + aldA, xB0 = als[(size_t)s0 * 4 + hA + 2] + aldB;
        float xA1 = als[(size_t)s1 * 4 + hA] + aldA, xB1 = als[(size_t)s1 * 4 + hA + 2] + aldB;
        float xA2 = als[(size_t)s2 * 4 + hA] + aldA, xB2 = als[(size_t)s2 * 4 + hA + 2] + aldB;
        float xA3 = als[(size_t)s3 * 4 + hA] + aldA, xB3 = als[(size_t)s3 * 4 + hA + 2] + aldB;
        xA0 = (xA0 > 0.f) ? xA0 : SLOPE * xA0;  xB0 = (xB0 > 0.f) ? xB0 : SLOPE * xB0;
        xA1 = (xA1 > 0.f) ? xA1 : SLOPE * xA1;  xB1 = (xB1 > 0.f) ? xB1 : SLOPE * xB1;
        xA2 = (xA2 > 0.f) ? xA2 : SLOPE * xA2;  xB2 = (xB2 > 0.f) ? xB2 : SLOPE * xB2;
        xA3 = (xA3 > 0.f) ? xA3 : SLOPE * xA3;  xB3 = (xB3 > 0.f) ? xB3 : SLOPE * xB3;
        float wA0 = __expf(xA0), wB0 = __expf(xB0);
        float wA1 = __expf(xA1), wB1 = __expf(xB1);
        float wA2 = __expf(xA2), wB2 = __expf(xB2);
        float wA3 = __expf(xA3), wB3 = __expf(xB3);
        denA += (wA0 + wA1) + (wA2 + wA3);
        denB += (wB0 + wB1) + (wB2 + wB3);
        #pragma unroll
        for (int c = 0; c < 8; ++c) {
            accA[c] += wA0 * bf2f((unsigned short)a0[c]) + wA1 * bf2f((unsigned short)a1[c])
                     + wA2 * bf2f((unsigned short)a2[c]) + wA3 * bf2f((unsigned short)a3[c]);
            accB[c] += wB0 * bf2f((unsigned short)b0[c]) + wB1 * bf2f((unsigned short)b1[c])
                     + wB2 * bf2f((unsigned short)b2[c]) + wB3 * bf2f((unsigned short)b3[c]);
        }
    }
    for (; j < e1; ++j) {
        int s0 = ssrc[j];
        const __hip_bfloat16* r0 = Hm + (size_t)s0 * 256 + q * 8;
        bf16x8 a0 = *reinterpret_cast<const bf16x8*>(r0);
        bf16x8 b0 = *reinterpret_cast<const bf16x8*>(r0 + 128);
        float xA0 = als[(size_t)s0 * 4 + hA] + aldA, xB0 = als[(size_t)s0 * 4 + hA + 2] + aldB;
        xA0 = (xA0 > 0.f) ? xA0 : SLOPE * xA0;  xB0 = (xB0 > 0.f) ? xB0 : SLOPE * xB0;
        float wA0 = __expf(xA0), wB0 = __expf(xB0);
        denA += wA0; denB += wB0;
        #pragma unroll
        for (int c = 0; c < 8; ++c) {
            accA[c] += wA0 * bf2f((unsigned short)a0[c]);
            accB[c] += wB0 * bf2f((unsigned short)b0[c]);
        }
    }

    float invA = 1.f / (denA + 1e-16f);
    float invB = 1.f / (denB + 1e-16f);

    float4 bA0 = *reinterpret_cast<const float4*>(bias + q * 8);
    float4 bA1 = *reinterpret_cast<const float4*>(bias + q * 8 + 4);
    float4 bB0 = *reinterpret_cast<const float4*>(bias + 128 + q * 8);
    float4 bB1 = *reinterpret_cast<const float4*>(bias + 128 + q * 8 + 4);
    __hip_bfloat16 oA[8], oB[8];
    oA[0] = __float2bfloat16(fmaxf(accA[0] * invA + bA0.x, 0.f));
    oA[1] = __float2bfloat16(fmaxf(accA[1] * invA + bA0.y, 0.f));
    oA[2] = __float2bfloat16(fmaxf(accA[2] * invA + bA0.z, 0.f));
    oA[3] = __float2bfloat16(fmaxf(accA[3] * invA + bA0.w, 0.f));
    oA[4] = __float2bfloat16(fmaxf(accA[4] * invA + bA1.x, 0.f));
    oA[5] = __float2bfloat16(fmaxf(accA[5] * invA + bA1.y, 0.f));
    oA[6] = __float2bfloat16(fmaxf(accA[6] * invA + bA1.z, 0.f));
    oA[7] = __float2bfloat16(fmaxf(accA[7] * invA + bA1.w, 0.f));
    oB[0] = __float2bfloat16(fmaxf(accB[0] * invB + bB0.x, 0.f));
    oB[1] = __float2bfloat16(fmaxf(accB[1] * invB + bB0.y, 0.f));
    oB[2] = __float2bfloat16(fmaxf(accB[2] * invB + bB0.z, 0.f));
    oB[3] = __float2bfloat16(fmaxf(accB[3] * invB + bB0.w, 0.f));
    oB[4] = __float2bfloat16(fmaxf(accB[4] * invB + bB1.x, 0.f));
    oB[5] = __float2bfloat16(fmaxf(accB[5] * invB + bB1.y, 0.f));
    oB[6] = __float2bfloat16(fmaxf(accB[6] * invB + bB1.z, 0.f));
    oB[7] = __float2bfloat16(fmaxf(accB[7] * invB + bB1.w, 0.f));
    __hip_bfloat16* op = Out + (size_t)d * 256 + q * 8;
    *reinterpret_cast<bf16x8*>(op)       = *reinterpret_cast<bf16x8*>(oA);
    *reinterpret_cast<bf16x8*>(op + 128) = *reinterpret_cast<bf16x8*>(oB);
}

// HC=128 (final layer, f32 out). CPL=8 is already packed.
__global__ __launch_bounds__(256) void attn128_kernel(const __hip_bfloat16* __restrict__ Hm,
                                                      const int* __restrict__ off,
                                                      const int* __restrict__ ssrc,
                                                      const float* __restrict__ als,
                                                      const float* __restrict__ ald,
                                                      const float* __restrict__ bias,
                                                      float* __restrict__ Out) {
    int wid  = threadIdx.x >> 6;
    int lane = threadIdx.x & 63;
    int g    = lane >> 4;
    int q    = lane & 15;
    int d    = blockIdx.x * 16 + wid * 4 + g;
    int head = q >> 2;

    int e0 = off[d], e1 = off[d + 1];
    float aldh = ald[(size_t)d * 4 + head];

    float acc[8];
    #pragma unroll
    for (int c = 0; c < 8; ++c) acc[c] = 0.f;
    float den = 0.f;

    int j = e0;
    for (; j + 3 < e1; j += 4) {
        int s0 = ssrc[j], s1 = ssrc[j + 1], s2 = ssrc[j + 2], s3 = ssrc[j + 3];
        bf16x8 a0 = *reinterpret_cast<const bf16x8*>(Hm + (size_t)s0 * 128 + q * 8);
        bf16x8 a1 = *reinterpret_cast<const bf16x8*>(Hm + (size_t)s1 * 128 + q * 8);
        bf16x8 a2 = *reinterpret_cast<const bf16x8*>(Hm + (size_t)s2 * 128 + q * 8);
        bf16x8 a3 = *reinterpret_cast<const bf16x8*>(Hm + (size_t)s3 * 128 + q * 8);
        float x0 = als[(size_t)s0 * 4 + head] + aldh;
        float x1 = als[(size_t)s1 * 4 + head] + aldh;
        float x2 = als[(size_t)s2 * 4 + head] + aldh;
        float x3 = als[(size_t)s3 * 4 + head] + aldh;
        x0 = (x0 > 0.f) ? x0 : SLOPE * x0;
        x1 = (x1 > 0.f) ? x1 : SLOPE * x1;
        x2 = (x2 > 0.f) ? x2 : SLOPE * x2;
        x3 = (x3 > 0.f) ? x3 : SLOPE * x3;
        float w0 = __expf(x0), w1 = __expf(x1), w2 = __expf(x2), w3 = __expf(x3);
        den += (w0 + w1) + (w2 + w3);
        #pragma unroll
        for (int c = 0; c < 8; ++c)
            acc[c] += w0 * bf2f((unsigned short)a0[c]) + w1 * bf2f((unsigned short)a1[c])
                    + w2 * bf2f((unsigned short)a2[c]) + w3 * bf2f((unsigned short)a3[c]);
    }
    for (; j < e1; ++j) {
        int s0 = ssrc[j];
        bf16x8 a0 = *reinterpret_cast<const bf16x8*>(Hm + (size_t)s0 * 128 + q * 8);
        float x0 = als[(size_t)s0 * 4 + head] + aldh;
        x0 = (x0 > 0.f) ? x0 : SLOPE * x0;
        float w0 = __expf(x0);
        den += w0;
        #pragma unroll
        for (int c = 0; c < 8; ++c) acc[c] += w0 * bf2f((unsigned short)a0[c]);
    }

    float inv = 1.f / (den + 1e-16f);
    float4 b0 = *reinterpret_cast<const float4*>(bias + q * 8);
    float4 b1 = *reinterpret_cast<const float4*>(bias + q * 8 + 4);
    float* op = Out + (size_t)d * 128 + q * 8;
    *reinterpret_cast<float4*>(op) = make_float4(
        fmaxf(acc[0] * inv + b0.x, 0.f), fmaxf(acc[1] * inv + b0.y, 0.f),
        fmaxf(acc[2] * inv + b0.z, 0.f), fmaxf(acc[3] * inv + b0.w, 0.f));
    *reinterpret_cast<float4*>(op + 4) = make_float4(
        fmaxf(acc[4] * inv + b1.x, 0.f), fmaxf(acc[5] * inv + b1.y, 0.f),
        fmaxf(acc[6] * inv + b1.z, 0.f), fmaxf(acc[7] * inv + b1.w, 0.f));
}

// ---------------------------------------------------------------- batch norm (bf16 input)
__global__ __launch_bounds__(256) void bnstats_kernel(const __hip_bfloat16* __restrict__ X,
                                                      float* __restrict__ sums) {
    int c  = threadIdx.x;
    int r0 = blockIdx.x * 200;
    float s = 0.f, q = 0.f;
    for (int r = r0; r < r0 + 200; ++r) {
        float v = bf2f(*(const unsigned short*)(X + (size_t)r * 256 + c));
        s += v; q += v * v;
    }
    atomicAdd(&sums[c], s);
    atomicAdd(&sums[256 + c], q);
}

// ---------------------------------------------------------------- launch

extern "C" void kernel_launch(void* const* d_in, const int* in_sizes, int n_in,
                              void* d_out, int out_size, void* d_ws, size_t ws_size,
                              hipStream_t stream) {
    const float* x      = (const float*)d_in[0];
    const int*   ei     = (const int*)d_in[1];
    const float* W1     = (const float*)d_in[2];
    const float* a_s1   = (const float*)d_in[3];
    const float* a_d1   = (const float*)d_in[4];
    const float* b1     = (const float*)d_in[5];
    const float* W2     = (const float*)d_in[6];
    const float* a_s2   = (const float*)d_in[7];
    const float* a_d2   = (const float*)d_in[8];
    const float* b2     = (const float*)d_in[9];
    const float* W3     = (const float*)d_in[10];
    const float* a_s3   = (const float*)d_in[11];
    const float* a_d3   = (const float*)d_in[12];
    const float* b3     = (const float*)d_in[13];
    const float* gamma1 = (const float*)d_in[14];
    const float* beta1  = (const float*)d_in[15];
    const float* gamma2 = (const float*)d_in[16];
    const float* beta2  = (const float*)d_in[17];

    char* ws = (char*)d_ws;
    size_t o = 0;
    auto alloc = [&](size_t bytes) -> void* {
        void* p = ws + o;
        o = (o + bytes + 255) & ~size_t(255);
        return p;
    };
    __hip_bfloat16*  Abf  = (__hip_bfloat16*)alloc((size_t)NP * 256 * 2);
    __hip_bfloat16*  Hbf  = (__hip_bfloat16*)alloc((size_t)NP * 256 * 2);
    __hip_bfloat16*  Xbf  = (__hip_bfloat16*)alloc((size_t)NP * 128 * 2);
    __hip_bfloat16*  WT1  = (__hip_bfloat16*)alloc((size_t)256 * 128 * 2);
    __hip_bfloat16*  WT2  = (__hip_bfloat16*)alloc((size_t)256 * 256 * 2);
    __hip_bfloat16*  WT3  = (__hip_bfloat16*)alloc((size_t)128 * 256 * 2);
    float* bb2   = (float*)alloc(256 * 4);
    float* bb3   = (float*)alloc(128 * 4);
    float* als   = (float*)alloc((size_t)NP * 4 * 4);
    float* ald   = (float*)alloc((size_t)NP * 4 * 4);
    float* sums  = (float*)alloc(512 * 4);
    int*   off   = (int*)alloc((size_t)(NN + 1) * 4);
    int*   cur   = (int*)alloc((size_t)NN * 4);
    int*   cnt   = (int*)alloc((size_t)NN * 4);
    int*   bsum  = (int*)alloc((size_t)NBLK * 4);
    int*   bexc  = (int*)alloc((size_t)NBLK * 4);
    int*   ssrc  = (int*)alloc((size_t)ETOT * 4);
    (void)ws_size; (void)in_sizes; (void)n_in; (void)out_size;

    const int EB = (ETOT + 255) / 256;

    // --- CSR build (shared by all 3 layers)
    hipMemsetAsync(cnt, 0, (size_t)NN * 4, stream);
    count_kernel<<<EB, 256, 0, stream>>>(ei, cnt);
    scanA_kernel<<<NBLK, 256, 0, stream>>>(cnt, off, bsum);
    scanB_kernel<<<1, 256, 0, stream>>>(bsum, bexc, off);
    scanC_kernel<<<NBLK, 256, 0, stream>>>(bexc, off, cur);
    fill_kernel<<<EB, 256, 0, stream>>>(ei, cur, ssrc);

    // --- layer 1
    castwx_kernel<<<XB + 128, 256, 0, stream>>>(x, W1, Xbf, WT1);
    mgemm_kernel<128, 256, false><<<dim3(NP / 128, 2), 256, 0, stream>>>(
        Xbf, WT1, nullptr, a_s1, a_d1, Hbf, als, ald);
    attn256_kernel<<<NN / 16, 256, 0, stream>>>(Hbf, off, ssrc, als, ald, b1, Abf);

    hipMemsetAsync(sums, 0, 512 * 4, stream);
    bnstats_kernel<<<250, 256, 0, stream>>>(Abf, sums);
    foldw_kernel<256><<<256, 256, 0, stream>>>(W2, sums, gamma1, beta1, WT2, bb2);

    // --- layer 2 (BN folded into WT2/bb2)
    mgemm_kernel<256, 256, true><<<dim3(NP / 128, 2), 256, 0, stream>>>(
        Abf, WT2, bb2, a_s2, a_d2, Hbf, als, ald);
    attn256_kernel<<<NN / 16, 256, 0, stream>>>(Hbf, off, ssrc, als, ald, b2, Abf);

    hipMemsetAsync(sums, 0, 512 * 4, stream);
    bnstats_kernel<<<250, 256, 0, stream>>>(Abf, sums);
    foldw_kernel<128><<<128, 256, 0, stream>>>(W3, sums, gamma2, beta2, WT3, bb3);

    // --- layer 3 (BN folded into WT3/bb3), f32 output
    mgemm_kernel<256, 128, true><<<dim3(NP / 128, 1), 256, 0, stream>>>(
        Abf, WT3, bb3, a_s3, a_d3, Hbf, als, ald);
    attn128_kernel<<<NN / 16, 256, 0, stream>>>(Hbf, off, ssrc, als, ald, b3, (float*)d_out);
}